// Round 12
// baseline (2907.328 us; speedup 1.0000x reference)
//
#include <hip/hip_runtime.h>
#include <hip/hip_bf16.h>

// GNNClassifier: 2x GRU(scan, fused+pipelined) -> GAT -> LN -> MHA -> pool -> FC
// B=16 T=1024 IN=64 H=256 G3=768 K=4 F=64 NH=4 HD=64 C=2
// Round-12: ROOT CAUSE of rounds 7-11 failures was a LAUNCHER transcription bug
// (qkv gemm16 called with N=H_=256 instead of N=G3_=768 since round 7 -> aliased
// racy writes, absmax~0.3 varying run-to-run). fused_gru was never the bug;
// round 11 proved it (round-6 fused_gru + stronger atomics, same failure).
// This round: round-10's overlapped-GEMM fused_gru + FIXED launcher (N=G3_).

#define B_ 16
#define T_ 1024
#define IN_ 64
#define H_ 256
#define G3_ 768
#define CHUNK 64
#define NCH (T_ / CHUNK)

typedef _Float16 f16x8 __attribute__((ext_vector_type(8)));
typedef float f32x4 __attribute__((ext_vector_type(4)));

__device__ __forceinline__ float fastrcp(float x) { return __builtin_amdgcn_rcpf(x); }
__device__ __forceinline__ float sigmoidf_(float x) { return fastrcp(1.f + __expf(-x)); }
__device__ __forceinline__ float tanh_fast(float x) {
    float t = __expf(-2.f * fabsf(x));
    float r = (1.f - t) * fastrcp(1.f + t);
    return x >= 0.f ? r : -r;
}

__device__ __forceinline__ f16x8 pack8(float4 a, float4 b) {
    f16x8 v;
    v[0] = (_Float16)a.x; v[1] = (_Float16)a.y; v[2] = (_Float16)a.z; v[3] = (_Float16)a.w;
    v[4] = (_Float16)b.x; v[5] = (_Float16)b.y; v[6] = (_Float16)b.z; v[7] = (_Float16)b.w;
    return v;
}

// ---------------- f16-MFMA tiled GEMM: Y[M][N] = X[M][Kd] @ W[N][Kd]^T + bias ----------------
__global__ __launch_bounds__(256) void gemm16(
    const float* __restrict__ X, const float* __restrict__ W,
    const float* __restrict__ bias, float* __restrict__ Y,
    int M, int N, int Kd)
{
    __shared__ _Float16 As[2][64][40];
    __shared__ _Float16 Bs[2][64][40];
    const int tid = threadIdx.x;
    const int wv = tid >> 6, lane = tid & 63;
    const int col = lane & 15, hi = lane >> 4;
    const int bm = blockIdx.y * 64, bn = blockIdx.x * 64;
    const int srow = tid >> 2, scol = (tid & 3) * 8;
    const float* xrow = X + (size_t)(bm + srow) * Kd + scol;
    const float* wrow = W + (size_t)(bn + srow) * Kd + scol;
    const int nk = Kd >> 5;

    {
        float4 a0 = *(const float4*)(xrow);
        float4 a1 = *(const float4*)(xrow + 4);
        float4 b0 = *(const float4*)(wrow);
        float4 b1 = *(const float4*)(wrow + 4);
        *(f16x8*)&As[0][srow][scol] = pack8(a0, a1);
        *(f16x8*)&Bs[0][srow][scol] = pack8(b0, b1);
    }
    __syncthreads();
    f32x4 acc[4] = {};
    for (int kc = 0; kc < nk; ++kc) {
        const int cur = kc & 1;
        f16x8 va, vb;
        const bool have = (kc + 1 < nk);
        if (have) {
            const float* xa = xrow + (kc + 1) * 32;
            const float* wa = wrow + (kc + 1) * 32;
            float4 a0 = *(const float4*)xa, a1 = *(const float4*)(xa + 4);
            float4 b0 = *(const float4*)wa, b1 = *(const float4*)(wa + 4);
            va = pack8(a0, a1);
            vb = pack8(b0, b1);
        }
        f16x8 a = *(const f16x8*)&As[cur][wv * 16 + col][hi * 8];
        #pragma unroll
        for (int j = 0; j < 4; ++j) {
            f16x8 bfr = *(const f16x8*)&Bs[cur][j * 16 + col][hi * 8];
            acc[j] = __builtin_amdgcn_mfma_f32_16x16x32_f16(a, bfr, acc[j], 0, 0, 0);
        }
        if (have) {
            *(f16x8*)&As[cur ^ 1][srow][scol] = va;
            *(f16x8*)&Bs[cur ^ 1][srow][scol] = vb;
        }
        __syncthreads();
    }
    #pragma unroll
    for (int j = 0; j < 4; ++j) {
        const int n = bn + j * 16 + col;
        const float bv = bias ? bias[n] : 0.f;
        #pragma unroll
        for (int r = 0; r < 4; ++r) {
            const int m = bm + wv * 16 + hi * 4 + r;
            Y[(size_t)m * N + n] = acc[j][r] + bv;
        }
    }
}

// ---------------- fused pipelined GRU scans (round-6 protocol + GEMM overlap) ----------------
// Blocks 0..15: layer-0 scan for batch b, h1 chunk kept in hchunk[c&1].
// During scan steps tt=0..23 of chunk c (c>0), the xp1 GEMM for chunk c-1 is
// executed one (j,mt)-slice per wave per step from hchunk[(c&1)^1]. At tt==24:
// full vmcnt drain + barrier + release flag[b][c-1]. Last chunk's GEMM runs
// serially after its scan. Blocks 16..31: layer-1 scan (round-6 verbatim).
__global__ __launch_bounds__(512, 2) void fused_gru(
    float* xp,                       // [B][T][768] xp0 in, overwritten by xp1 per chunk
    const float* __restrict__ w_hh0, const float* __restrict__ b_hh0,
    const float* __restrict__ w_hh1, const float* __restrict__ b_hh1,
    const _Float16* __restrict__ w_ih1h, const float* __restrict__ b_ih1,
    float* __restrict__ ys,          // [B][T][256] gru_out
    int* flags)                      // [B][NCH]
{
    __shared__ _Float16 hbuf[2][272];
    __shared__ _Float16 hchunk[2][CHUNK][264];   // double-buffered; 528B rows (16B-aligned)
    const int tid = threadIdx.x;
    const int lane = tid & 63;
    const int wv = tid >> 6;     // wave 0..7
    const int col = lane & 15;
    const int hi = lane >> 4;
    const bool isL0 = blockIdx.x < 16;
    const int b = isL0 ? blockIdx.x : blockIdx.x - 16;

    const float* wm = isL0 ? w_hh0 : w_hh1;
    const float* bb = isL0 ? b_hh0 : b_hh1;

    // recurrent weight fragments (this thread's 2 units x 3 gates)
    f16x8 bf[3][2][8];
    float bias_[3][2];
    #pragma unroll
    for (int g = 0; g < 3; ++g) {
        #pragma unroll
        for (int q = 0; q < 2; ++q) {
            const int n = g * 256 + wv * 32 + q * 16 + col;
            bias_[g][q] = bb[n];
            #pragma unroll
            for (int c = 0; c < 8; ++c) {
                const float* src = wm + (size_t)n * 256 + c * 32 + hi * 8;
                float4 u0 = *(const float4*)(src);
                float4 u1 = *(const float4*)(src + 4);
                bf[g][q][c] = pack8(u0, u1);
            }
        }
    }
    // xp1-GEMM bias (L0 only; wave wv owns n-tiles wv*6..wv*6+5)
    float bias1_[6];
    #pragma unroll
    for (int j = 0; j < 6; ++j) bias1_[j] = b_ih1[(wv * 6 + j) * 16 + col];

    float hold[2] = {0.f, 0.f};
    if (tid < 256) hbuf[0][tid] = (_Float16)0.f;
    __syncthreads();

    float* xbase = xp + (size_t)b * T_ * G3_;
    float* ybase = ys + (size_t)b * T_ * H_;

    float pref[3][2];
    if (isL0) {
        #pragma unroll
        for (int g = 0; g < 3; ++g)
            #pragma unroll
            for (int q = 0; q < 2; ++q)
                pref[g][q] = xbase[g * 256 + wv * 32 + q * 16 + col];
    }

    int cur = 0;
    for (int c = 0; c < NCH; ++c) {
        const int t0 = c * CHUNK;
        const int hc = c & 1;
        if (!isL0) {
            // wait for xp1 chunk c from the L0 block of this batch
            if (tid == 0) {
                while (__hip_atomic_load(&flags[b * NCH + c], __ATOMIC_ACQUIRE,
                                         __HIP_MEMORY_SCOPE_AGENT) == 0) {
                    __builtin_amdgcn_s_sleep(16);
                }
                __threadfence();
            }
            __syncthreads();
            #pragma unroll
            for (int g = 0; g < 3; ++g)
                #pragma unroll
                for (int q = 0; q < 2; ++q)
                    pref[g][q] = xbase[(size_t)t0 * G3_ + g * 256 + wv * 32 + q * 16 + col];
        }
        for (int tt = 0; tt < CHUNK; ++tt) {
            const int t = t0 + tt;
            float xv[3][2];
            #pragma unroll
            for (int g = 0; g < 3; ++g)
                #pragma unroll
                for (int q = 0; q < 2; ++q)
                    xv[g][q] = pref[g][q];
            // prefetch next step (L0: global next; L1: clamp inside ready chunk)
            const int tn = isL0 ? ((t < T_ - 1) ? t + 1 : t)
                                : ((tt < CHUNK - 1) ? t + 1 : t);
            #pragma unroll
            for (int g = 0; g < 3; ++g)
                #pragma unroll
                for (int q = 0; q < 2; ++q)
                    pref[g][q] = xbase[(size_t)tn * G3_ + g * 256 + wv * 32 + q * 16 + col];

            f32x4 acc[3][2] = {};
            #pragma unroll
            for (int cc = 0; cc < 8; ++cc) {
                f16x8 a = *(const f16x8*)(&hbuf[cur][cc * 32 + hi * 8]); // broadcast A
                #pragma unroll
                for (int g = 0; g < 3; ++g)
                    #pragma unroll
                    for (int q = 0; q < 2; ++q)
                        acc[g][q] = __builtin_amdgcn_mfma_f32_16x16x32_f16(a, bf[g][q][cc], acc[g][q], 0, 0, 0);
            }

            const int nxt = cur ^ 1;
            #pragma unroll
            for (int q = 0; q < 2; ++q) {
                const int unit = wv * 32 + q * 16 + col;
                float ghr = acc[0][q][0] + bias_[0][q];
                float ghz = acc[1][q][0] + bias_[1][q];
                float ghn = acc[2][q][0] + bias_[2][q];
                float r = sigmoidf_(xv[0][q] + ghr);
                float z = sigmoidf_(xv[1][q] + ghz);
                float nn = tanh_fast(xv[2][q] + r * ghn);
                float hv = (1.f - z) * nn + z * hold[q];
                hold[q] = hv;
                if (hi == 0) {
                    hbuf[nxt][unit] = (_Float16)hv;
                    if (isL0) hchunk[hc][tt][unit] = (_Float16)hv;
                    else      ybase[(size_t)t * H_ + unit] = hv;
                }
            }
            // overlapped GEMM slice for chunk c-1 (L0, steps 0..23): one (j,mt)
            // unit per wave per step, reading the OTHER hchunk buffer (complete
            // and immutable during chunk c). Same arithmetic/addresses as the
            // verified serial GEMM.
            if (isL0 && c > 0 && tt < 24) {
                const int j = tt >> 2, mt = tt & 3;
                const int n = (wv * 6 + j) * 16 + col;
                const int t0m = t0 - CHUNK;
                f32x4 ga = {};
                #pragma unroll
                for (int kk = 0; kk < 8; ++kk) {
                    f16x8 bfr = *(const f16x8*)(w_ih1h + (size_t)n * 256 + kk * 32 + hi * 8);
                    f16x8 a = *(const f16x8*)&hchunk[hc ^ 1][mt * 16 + col][kk * 32 + hi * 8];
                    ga = __builtin_amdgcn_mfma_f32_16x16x32_f16(a, bfr, ga, 0, 0, 0);
                }
                const float bv = bias1_[j];
                #pragma unroll
                for (int r = 0; r < 4; ++r)
                    xbase[(size_t)(t0m + mt * 16 + hi * 4 + r) * G3_ + n] = ga[r] + bv;
            }
            // barrier. At tt==24 (L0, c>0): full drain, then release flag[c-1].
            // Branch is block-uniform (isL0/c/tt uniform within a block).
            if (isL0 && c > 0 && tt == 24) {
                asm volatile("s_waitcnt vmcnt(0) lgkmcnt(0)" ::: "memory");
                __builtin_amdgcn_s_barrier();
                asm volatile("" ::: "memory");
                if (tid == 0) {
                    __threadfence();
                    __hip_atomic_store(&flags[b * NCH + (c - 1)], 1, __ATOMIC_RELEASE,
                                       __HIP_MEMORY_SCOPE_AGENT);
                }
            } else {
                asm volatile("s_waitcnt lgkmcnt(0)" ::: "memory");
                __builtin_amdgcn_s_barrier();
                asm volatile("" ::: "memory");
            }
            cur = nxt;
        }
        if (isL0 && c == NCH - 1) {
            // last chunk: serial GEMM (verified round-6 code) on hchunk[hc]
            #pragma unroll
            for (int j = 0; j < 6; ++j) {
                const int n = (wv * 6 + j) * 16 + col;
                f16x8 bfr[8];
                #pragma unroll
                for (int kk = 0; kk < 8; ++kk)
                    bfr[kk] = *(const f16x8*)(w_ih1h + (size_t)n * 256 + kk * 32 + hi * 8);
                #pragma unroll
                for (int mt = 0; mt < 4; ++mt) {
                    f32x4 ga = {};
                    #pragma unroll
                    for (int kk = 0; kk < 8; ++kk) {
                        f16x8 a = *(const f16x8*)&hchunk[hc][mt * 16 + col][kk * 32 + hi * 8];
                        ga = __builtin_amdgcn_mfma_f32_16x16x32_f16(a, bfr[kk], ga, 0, 0, 0);
                    }
                    #pragma unroll
                    for (int r = 0; r < 4; ++r)
                        xbase[(size_t)(t0 + mt * 16 + hi * 4 + r) * G3_ + n] = ga[r] + bias1_[j];
                }
            }
            asm volatile("s_waitcnt vmcnt(0)" ::: "memory");
            __syncthreads();
            if (tid == 0) {
                __threadfence();
                __hip_atomic_store(&flags[b * NCH + c], 1, __ATOMIC_RELEASE,
                                   __HIP_MEMORY_SCOPE_AGENT);
            }
        }
    }
}

// ---------------- prep: gat_W transpose + w_ih1 -> f16 ----------------
__global__ void gatw_t(const float* __restrict__ gw, float* __restrict__ W2)
{
    int idx = blockIdx.x * 256 + threadIdx.x;
    int n = idx >> 8, d = idx & 255;
    W2[idx] = gw[(size_t)(n >> 6) * 16384 + (size_t)d * 64 + (n & 63)];
}

__global__ void prep_wih1(const float* __restrict__ w, _Float16* __restrict__ wh)
{
    int i = (blockIdx.x * 256 + threadIdx.x) * 4; // 196608 elems
    float4 v = *(const float4*)(w + i);
    wh[i + 0] = (_Float16)v.x; wh[i + 1] = (_Float16)v.y;
    wh[i + 2] = (_Float16)v.z; wh[i + 3] = (_Float16)v.w;
}

// ---------------- e1/e2 ----------------
__global__ __launch_bounds__(256) void gat_e(
    const float* __restrict__ hk, const float* __restrict__ ga,
    float* __restrict__ e1, float* __restrict__ e2)
{
    __shared__ float tile[128][65];
    __shared__ float a1s[64], a2s[64];
    const int tt = blockIdx.x, k = blockIdx.y, b = blockIdx.z;
    const int tid = threadIdx.x;
    if (tid < 64) { a1s[tid] = ga[k * 128 + tid]; a2s[tid] = ga[k * 128 + 64 + tid]; }
    #pragma unroll
    for (int rep = 0; rep < 32; ++rep) {
        int idx = rep * 256 + tid; int tl = idx >> 6, f = idx & 63;
        tile[tl][f] = hk[((size_t)(b * 1024 + tt * 128 + tl)) * 256 + k * 64 + f];
    }
    __syncthreads();
    if (tid < 128) {
        float s1 = 0.f, s2 = 0.f;
        #pragma unroll 8
        for (int f = 0; f < 64; ++f) {
            float hv = tile[tid][f];
            s1 += hv * a1s[f]; s2 += hv * a2s[f];
        }
        const size_t o = (size_t)(b * 4 + k) * 1024 + tt * 128 + tid;
        e1[o] = s1; e2[o] = s2;
    }
}

// ---------------- GAT attention (MFMA PV, monotone-leaky exact max) ----------------
__global__ __launch_bounds__(256) void gat_attn(
    const float* __restrict__ hk, const float* __restrict__ e1,
    const float* __restrict__ e2, float* __restrict__ outp)
{
    __shared__ _Float16 hkT[64][72];
    __shared__ float e1s[64], e2s[64], lssh[64];
    __shared__ float red[4];
    const int tid = threadIdx.x;
    const int wv = tid >> 6, lane = tid & 63;
    const int col = lane & 15, hi = lane >> 4;
    const int tt = blockIdx.x, k = blockIdx.y, b = blockIdx.z;
    const int t0 = tt * 64;
    const float* e2row = e2 + (size_t)(b * 4 + k) * 1024;
    if (tid < 64) e1s[tid] = e1[(size_t)(b * 4 + k) * 1024 + t0 + tid];
    float m = -3.4e38f;
    for (int i = tid; i < 1024; i += 256) m = fmaxf(m, e2row[i]);
    #pragma unroll
    for (int off = 1; off < 64; off <<= 1) m = fmaxf(m, __shfl_xor(m, off));
    if (lane == 0) red[wv] = m;
    __syncthreads();
    const float e2max = fmaxf(fmaxf(red[0], red[1]), fmaxf(red[2], red[3]));
    const float e1A = e1s[wv * 16 + col];
    const float eAm = e1A + e2max;
    const float mA = (eAm > 0.f) ? eAm : 0.2f * eAm;

    float lsum = 0.f;
    f32x4 oacc[4] = {};
    const int vs = tid & 63, vfblk = (tid >> 6) * 16;
    for (int st = 0; st < 16; ++st) {
        {
            const float* hp = hk + ((size_t)(b * 1024 + st * 64 + vs)) * 256 + k * 64 + vfblk;
            float4 v0 = *(const float4*)hp, v1 = *(const float4*)(hp + 4);
            float4 v2 = *(const float4*)(hp + 8), v3 = *(const float4*)(hp + 12);
            float vv[16] = {v0.x, v0.y, v0.z, v0.w, v1.x, v1.y, v1.z, v1.w,
                            v2.x, v2.y, v2.z, v2.w, v3.x, v3.y, v3.z, v3.w};
            #pragma unroll
            for (int i = 0; i < 16; ++i) hkT[vfblk + i][vs] = (_Float16)vv[i];
        }
        if (tid < 64) e2s[tid] = e2row[st * 64 + tid];
        __syncthreads();
        #pragma unroll
        for (int c = 0; c < 2; ++c) {
            f16x8 af;
            #pragma unroll
            for (int i = 0; i < 8; ++i) {
                float e = e1A + e2s[c * 32 + hi * 8 + i];
                e = (e > 0.f) ? e : 0.2f * e;
                float pv = __expf(e - mA);
                _Float16 p16 = (_Float16)pv;
                af[i] = p16;
                lsum += (float)p16;
            }
            #pragma unroll
            for (int j = 0; j < 4; ++j) {
                f16x8 bfr = *(const f16x8*)&hkT[j * 16 + col][c * 32 + hi * 8];
                oacc[j] = __builtin_amdgcn_mfma_f32_16x16x32_f16(af, bfr, oacc[j], 0, 0, 0);
            }
        }
        __syncthreads();
    }
    lsum += __shfl_xor(lsum, 16);
    lsum += __shfl_xor(lsum, 32);
    if (hi == 0) lssh[wv * 16 + col] = lsum;
    #pragma unroll
    for (int r = 0; r < 4; ++r) {
        const float inv = 1.f / lssh[wv * 16 + hi * 4 + r];
        #pragma unroll
        for (int j = 0; j < 4; ++j)
            outp[((size_t)(b * 1024 + t0 + wv * 16 + hi * 4 + r)) * 256 + k * 64 + j * 16 + col]
                = oacc[j][r] * inv;
    }
}

// ---------------- residual + LayerNorm ----------------
__global__ __launch_bounds__(64) void add_ln(
    const float* __restrict__ a, const float* bb,
    const float* __restrict__ gamma, const float* __restrict__ beta,
    float* outp)
{
    const int row = blockIdx.x;
    const int lane = threadIdx.x;
    const size_t base = (size_t)row * 256 + lane * 4;
    float4 va = *(const float4*)(a + base);
    float4 vb = *(const float4*)(bb + base);
    float xv[4] = {va.x + vb.x, va.y + vb.y, va.z + vb.z, va.w + vb.w};
    float s = xv[0] + xv[1] + xv[2] + xv[3];
    float s2 = xv[0] * xv[0] + xv[1] * xv[1] + xv[2] * xv[2] + xv[3] * xv[3];
    #pragma unroll
    for (int off = 32; off >= 1; off >>= 1) {
        s += __shfl_xor(s, off);
        s2 += __shfl_xor(s2, off);
    }
    const float mu = s * (1.f / 256.f);
    const float var = s2 * (1.f / 256.f) - mu * mu;
    const float rs = rsqrtf(var + 1e-5f);
    float4 g4 = *(const float4*)(gamma + lane * 4);
    float4 b4 = *(const float4*)(beta + lane * 4);
    float4 ov;
    ov.x = (xv[0] - mu) * rs * g4.x + b4.x;
    ov.y = (xv[1] - mu) * rs * g4.y + b4.y;
    ov.z = (xv[2] - mu) * rs * g4.z + b4.z;
    ov.w = (xv[3] - mu) * rs * g4.w + b4.w;
    *(float4*)(outp + base) = ov;
}

// ---------------- MHA flash attention (MFMA QK^T + PV) ----------------
__global__ __launch_bounds__(256) void mha_attn(const float* __restrict__ qkv, float* __restrict__ o)
{
    __shared__ _Float16 ks[64][72];
    __shared__ _Float16 vts[64][72];
    __shared__ _Float16 ps[64][72];
    const int tid = threadIdx.x;
    const int wv = tid >> 6, lane = tid & 63;
    const int col = lane & 15, hi = lane >> 4;
    const int tt = blockIdx.x, h = blockIdx.y, b = blockIdx.z;
    const int t0 = tt * 64;
    const float* base = qkv + (size_t)b * 1024 * 768;

    f16x8 qf[2];
    #pragma unroll
    for (int c = 0; c < 2; ++c) {
        const float* src = base + (size_t)(t0 + wv * 16 + col) * 768 + h * 64 + c * 32 + hi * 8;
        float4 u0 = *(const float4*)src, u1 = *(const float4*)(src + 4);
        u0.x *= 0.125f; u0.y *= 0.125f; u0.z *= 0.125f; u0.w *= 0.125f;
        u1.x *= 0.125f; u1.y *= 0.125f; u1.z *= 0.125f; u1.w *= 0.125f;
        qf[c] = pack8(u0, u1);
    }
    f32x4 oacc[4] = {};
    float mrow[4] = {-3.4e38f, -3.4e38f, -3.4e38f, -3.4e38f};
    float lrow[4] = {};
    const int srow = tid >> 2, sdblk = (tid & 3) * 16;
    const int vs = tid & 63, vdblk = (tid >> 6) * 16;

    for (int st = 0; st < 16; ++st) {
        {
            const float* kp = base + (size_t)(st * 64 + srow) * 768 + 256 + h * 64 + sdblk;
            float4 k0 = *(const float4*)kp, k1 = *(const float4*)(kp + 4);
            float4 k2 = *(const float4*)(kp + 8), k3 = *(const float4*)(kp + 12);
            *(f16x8*)&ks[srow][sdblk] = pack8(k0, k1);
            *(f16x8*)&ks[srow][sdblk + 8] = pack8(k2, k3);
            const float* vp = base + (size_t)(st * 64 + vs) * 768 + 512 + h * 64 + vdblk;
            float4 v0 = *(const float4*)vp, v1 = *(const float4*)(vp + 4);
            float4 v2 = *(const float4*)(vp + 8), v3 = *(const float4*)(vp + 12);
            float vv[16] = {v0.x, v0.y, v0.z, v0.w, v1.x, v1.y, v1.z, v1.w,
                            v2.x, v2.y, v2.z, v2.w, v3.x, v3.y, v3.z, v3.w};
            #pragma unroll
            for (int i = 0; i < 16; ++i) vts[vdblk + i][vs] = (_Float16)vv[i];
        }
        __syncthreads();
        f32x4 sacc[4] = {};
        #pragma unroll
        for (int c = 0; c < 2; ++c) {
            #pragma unroll
            for (int j = 0; j < 4; ++j) {
                f16x8 bfr = *(const f16x8*)&ks[j * 16 + col][c * 32 + hi * 8];
                sacc[j] = __builtin_amdgcn_mfma_f32_16x16x32_f16(qf[c], bfr, sacc[j], 0, 0, 0);
            }
        }
        #pragma unroll
        for (int r = 0; r < 4; ++r) {
            float tm = fmaxf(fmaxf(sacc[0][r], sacc[1][r]), fmaxf(sacc[2][r], sacc[3][r]));
            tm = fmaxf(tm, __shfl_xor(tm, 1));
            tm = fmaxf(tm, __shfl_xor(tm, 2));
            tm = fmaxf(tm, __shfl_xor(tm, 4));
            tm = fmaxf(tm, __shfl_xor(tm, 8));
            const float mn = fmaxf(mrow[r], tm);
            const float corr = __expf(mrow[r] - mn);
            mrow[r] = mn;
            float lsum = 0.f;
            #pragma unroll
            for (int j = 0; j < 4; ++j) {
                float pv = __expf(sacc[j][r] - mn);
                _Float16 p16 = (_Float16)pv;
                ps[wv * 16 + hi * 4 + r][j * 16 + col] = p16;
                lsum += (float)p16;
            }
            lsum += __shfl_xor(lsum, 1);
            lsum += __shfl_xor(lsum, 2);
            lsum += __shfl_xor(lsum, 4);
            lsum += __shfl_xor(lsum, 8);
            lrow[r] = lrow[r] * corr + lsum;
            #pragma unroll
            for (int j = 0; j < 4; ++j) oacc[j][r] *= corr;
        }
        #pragma unroll
        for (int c = 0; c < 2; ++c) {
            f16x8 a = *(const f16x8*)&ps[wv * 16 + col][c * 32 + hi * 8];
            #pragma unroll
            for (int j = 0; j < 4; ++j) {
                f16x8 bfr = *(const f16x8*)&vts[j * 16 + col][c * 32 + hi * 8];
                oacc[j] = __builtin_amdgcn_mfma_f32_16x16x32_f16(a, bfr, oacc[j], 0, 0, 0);
            }
        }
        __syncthreads();
    }
    float inv[4];
    #pragma unroll
    for (int r = 0; r < 4; ++r) inv[r] = 1.f / lrow[r];
    #pragma unroll
    for (int j = 0; j < 4; ++j)
        #pragma unroll
        for (int r = 0; r < 4; ++r)
            o[((size_t)(b * 1024 + t0 + wv * 16 + hi * 4 + r)) * 256 + h * 64 + j * 16 + col]
                = oacc[j][r] * inv[r];
}

// ---------------- mean over T ----------------
__global__ __launch_bounds__(256) void pool_mean(const float* __restrict__ o, float* __restrict__ opool)
{
    const int b = blockIdx.x >> 3, chunk = blockIdx.x & 7;
    const int d = threadIdx.x;
    float s = 0.f;
    for (int t = chunk * 128; t < chunk * 128 + 128; ++t)
        s += o[((size_t)(b * 1024 + t)) * 256 + d];
    atomicAdd(&opool[b * 256 + d], s * (1.f / 1024.f));
}

// ---------------- head ----------------
__global__ __launch_bounds__(256) void head_k(
    const float* __restrict__ opool, const float* __restrict__ wout, const float* __restrict__ bout,
    const float* __restrict__ f1w, const float* __restrict__ f1b,
    const float* __restrict__ f2w, const float* __restrict__ f2b,
    float* __restrict__ outp)
{
    __shared__ float op[256], pooled[256], hid[128];
    const int b = blockIdx.x, e = threadIdx.x;
    op[e] = opool[b * 256 + e];
    __syncthreads();
    float s = bout[e];
    for (int d = 0; d < 256; d += 4) {
        float4 w4 = *(const float4*)(wout + (size_t)e * 256 + d);
        s += op[d] * w4.x + op[d + 1] * w4.y + op[d + 2] * w4.z + op[d + 3] * w4.w;
    }
    pooled[e] = s;
    __syncthreads();
    if (e < 128) {
        float s2 = f1b[e];
        for (int d = 0; d < 256; d += 4) {
            float4 w4 = *(const float4*)(f1w + (size_t)e * 256 + d);
            s2 += pooled[d] * w4.x + pooled[d + 1] * w4.y + pooled[d + 2] * w4.z + pooled[d + 3] * w4.w;
        }
        hid[e] = fmaxf(s2, 0.f);
    }
    __syncthreads();
    if (e < 2) {
        float s3 = f2b[e];
        for (int j = 0; j < 128; ++j) s3 += hid[j] * f2w[e * 128 + j];
        outp[b * 2 + e] = s3;
    }
}

extern "C" void kernel_launch(void* const* d_in, const int* in_sizes, int n_in,
                              void* d_out, int out_size, void* d_ws, size_t ws_size,
                              hipStream_t stream)
{
    const float* x         = (const float*)d_in[0];
    const float* w_ih0     = (const float*)d_in[1];
    const float* w_hh0     = (const float*)d_in[2];
    const float* b_ih0     = (const float*)d_in[3];
    const float* b_hh0     = (const float*)d_in[4];
    const float* w_ih1     = (const float*)d_in[5];
    const float* w_hh1     = (const float*)d_in[6];
    const float* b_ih1     = (const float*)d_in[7];
    const float* b_hh1     = (const float*)d_in[8];
    const float* gat_W     = (const float*)d_in[9];
    const float* gat_a     = (const float*)d_in[10];
    const float* ln_g      = (const float*)d_in[11];
    const float* ln_b      = (const float*)d_in[12];
    const float* mha_in_w  = (const float*)d_in[13];
    const float* mha_in_b  = (const float*)d_in[14];
    const float* mha_out_w = (const float*)d_in[15];
    const float* mha_out_b = (const float*)d_in[16];
    const float* fc1_w     = (const float*)d_in[17];
    const float* fc1_b     = (const float*)d_in[18];
    const float* fc2_w     = (const float*)d_in[19];
    const float* fc2_b     = (const float*)d_in[20];
    float* out = (float*)d_out;

    float* xpbuf = (float*)d_ws;                       // [B*T][768] xp0 -> xp1 (in place)
    float* buf1  = xpbuf + (size_t)B_ * T_ * G3_;      // [B*T][256] (gat / h)
    float* buf2  = buf1 + (size_t)B_ * T_ * H_;        // [B*T][256] (gru_out)
    float* buf3  = buf2 + (size_t)B_ * T_ * H_;        // [B*T][256] (hk / o)
    float* W2    = buf3 + (size_t)B_ * T_ * H_;        // 65536
    float* e1    = W2 + 65536;
    float* e2    = e1 + 65536;
    float* opool = e2 + 65536;                         // 4096 floats
    int*   flags = (int*)(opool + 4096);               // 256 ints
    _Float16* wih1h = (_Float16*)(flags + 256);        // 196608 f16

    dim3 blk(256);
    gatw_t<<<dim3(256), blk, 0, stream>>>(gat_W, W2);
    prep_wih1<<<dim3(192), blk, 0, stream>>>(w_ih1, wih1h);
    // xp0 = x @ w_ih0^T + b_ih0   (M=B*T, N=G3, K=IN)
    gemm16<<<dim3(G3_ / 64, (B_ * T_) / 64), blk, 0, stream>>>(x, w_ih0, b_ih0, xpbuf, B_ * T_, G3_, IN_);
    // zero opool + flags (single contiguous region)
    hipMemsetAsync(opool, 0, 4096 * sizeof(float) + 256 * sizeof(int), stream);
    // fused pipelined scans: L0 (blocks 0-15) -> xp1 in place -> L1 (blocks 16-31) -> buf2
    fused_gru<<<dim3(32), dim3(512), 0, stream>>>(xpbuf, w_hh0, b_hh0, w_hh1, b_hh1,
                                                  wih1h, b_ih1, buf2, flags);
    // hk = gru_out @ W2^T -> buf3   (M=B*T, N=H, K=H)
    gemm16<<<dim3(H_ / 64, (B_ * T_) / 64), blk, 0, stream>>>(buf2, W2, nullptr, buf3, B_ * T_, H_, H_);
    gat_e<<<dim3(8, 4, 16), blk, 0, stream>>>(buf3, gat_a, e1, e2);
    gat_attn<<<dim3(16, 4, 16), blk, 0, stream>>>(buf3, e1, e2, buf1);
    add_ln<<<dim3(B_ * T_), dim3(64), 0, stream>>>(buf2, buf1, ln_g, ln_b, buf1);
    // qkv = h @ mha_in_w^T + b -> xpbuf   (M=B*T, N=G3 !!, K=H)  [the round-7..11 bug was N=H_]
    gemm16<<<dim3(G3_ / 64, (B_ * T_) / 64), blk, 0, stream>>>(buf1, mha_in_w, mha_in_b, xpbuf, B_ * T_, G3_, H_);
    mha_attn<<<dim3(16, 4, 16), blk, 0, stream>>>(xpbuf, buf3);
    pool_mean<<<dim3(128), blk, 0, stream>>>(buf3, opool);
    head_k<<<dim3(16), blk, 0, stream>>>(opool, mha_out_w, mha_out_b, fc1_w, fc1_b, fc2_w, fc2_b, out);
}

// Round 13
// 1878.291 us; speedup vs baseline: 1.5479x; 1.5479x over previous
//
#include <hip/hip_runtime.h>
#include <hip/hip_bf16.h>

// GNNClassifier: 2x GRU(scan, fused+pipelined) -> GAT -> LN -> MHA -> pool -> FC
// B=16 T=1024 IN=64 H=256 G3=768 K=4 F=64 NH=4 HD=64 C=2
// Round-13: round-6's VERIFIED fused_gru (2-stage, serial chunk-GEMM; round-12's
// overlap REVERTED: dependent w_ih1h-load->MFMA chains inside scan steps made it
// 2675us vs 1751us). One change: the serial chunk-GEMM uses the low-pressure
// schedule (j-outer, ONE bfr live at a time, 4 named f32x4 accumulators) --
// round 8's schedule, whose failure was the 266-stride misalignment, not this.
// hchunk stays at the 16B-aligned 264-f16 stride. Launcher has the round-12
// fix (qkv gemm16 N=G3_, the root cause of rounds 7-11).

#define B_ 16
#define T_ 1024
#define IN_ 64
#define H_ 256
#define G3_ 768
#define CHUNK 64
#define NCH (T_ / CHUNK)

typedef _Float16 f16x8 __attribute__((ext_vector_type(8)));
typedef float f32x4 __attribute__((ext_vector_type(4)));

__device__ __forceinline__ float fastrcp(float x) { return __builtin_amdgcn_rcpf(x); }
__device__ __forceinline__ float sigmoidf_(float x) { return fastrcp(1.f + __expf(-x)); }
__device__ __forceinline__ float tanh_fast(float x) {
    float t = __expf(-2.f * fabsf(x));
    float r = (1.f - t) * fastrcp(1.f + t);
    return x >= 0.f ? r : -r;
}

__device__ __forceinline__ f16x8 pack8(float4 a, float4 b) {
    f16x8 v;
    v[0] = (_Float16)a.x; v[1] = (_Float16)a.y; v[2] = (_Float16)a.z; v[3] = (_Float16)a.w;
    v[4] = (_Float16)b.x; v[5] = (_Float16)b.y; v[6] = (_Float16)b.z; v[7] = (_Float16)b.w;
    return v;
}

// ---------------- f16-MFMA tiled GEMM: Y[M][N] = X[M][Kd] @ W[N][Kd]^T + bias ----------------
__global__ __launch_bounds__(256) void gemm16(
    const float* __restrict__ X, const float* __restrict__ W,
    const float* __restrict__ bias, float* __restrict__ Y,
    int M, int N, int Kd)
{
    __shared__ _Float16 As[2][64][40];
    __shared__ _Float16 Bs[2][64][40];
    const int tid = threadIdx.x;
    const int wv = tid >> 6, lane = tid & 63;
    const int col = lane & 15, hi = lane >> 4;
    const int bm = blockIdx.y * 64, bn = blockIdx.x * 64;
    const int srow = tid >> 2, scol = (tid & 3) * 8;
    const float* xrow = X + (size_t)(bm + srow) * Kd + scol;
    const float* wrow = W + (size_t)(bn + srow) * Kd + scol;
    const int nk = Kd >> 5;

    {
        float4 a0 = *(const float4*)(xrow);
        float4 a1 = *(const float4*)(xrow + 4);
        float4 b0 = *(const float4*)(wrow);
        float4 b1 = *(const float4*)(wrow + 4);
        *(f16x8*)&As[0][srow][scol] = pack8(a0, a1);
        *(f16x8*)&Bs[0][srow][scol] = pack8(b0, b1);
    }
    __syncthreads();
    f32x4 acc[4] = {};
    for (int kc = 0; kc < nk; ++kc) {
        const int cur = kc & 1;
        f16x8 va, vb;
        const bool have = (kc + 1 < nk);
        if (have) {
            const float* xa = xrow + (kc + 1) * 32;
            const float* wa = wrow + (kc + 1) * 32;
            float4 a0 = *(const float4*)xa, a1 = *(const float4*)(xa + 4);
            float4 b0 = *(const float4*)wa, b1 = *(const float4*)(wa + 4);
            va = pack8(a0, a1);
            vb = pack8(b0, b1);
        }
        f16x8 a = *(const f16x8*)&As[cur][wv * 16 + col][hi * 8];
        #pragma unroll
        for (int j = 0; j < 4; ++j) {
            f16x8 bfr = *(const f16x8*)&Bs[cur][j * 16 + col][hi * 8];
            acc[j] = __builtin_amdgcn_mfma_f32_16x16x32_f16(a, bfr, acc[j], 0, 0, 0);
        }
        if (have) {
            *(f16x8*)&As[cur ^ 1][srow][scol] = va;
            *(f16x8*)&Bs[cur ^ 1][srow][scol] = vb;
        }
        __syncthreads();
    }
    #pragma unroll
    for (int j = 0; j < 4; ++j) {
        const int n = bn + j * 16 + col;
        const float bv = bias ? bias[n] : 0.f;
        #pragma unroll
        for (int r = 0; r < 4; ++r) {
            const int m = bm + wv * 16 + hi * 4 + r;
            Y[(size_t)m * N + n] = acc[j][r] + bv;
        }
    }
}

// ---------------- fused pipelined GRU scans (round-6 verified topology) ----------------
// Blocks 0..15: layer-0 scan for batch b. Per 64-step chunk: scan (h kept in LDS
// hchunk) -> serial xp1 = h1 @ w_ih1^T + b_ih1 written IN PLACE over the consumed
// xp0 chunk -> vmcnt(0) drain -> barrier -> release flag[b][c].
// Blocks 16..31: layer-1 scan; acquire-spins on flag[b][c] per chunk; writes gru_out.
__global__ __launch_bounds__(512, 2) void fused_gru(
    float* xp,                       // [B][T][768] xp0 in, overwritten by xp1 per chunk
    const float* __restrict__ w_hh0, const float* __restrict__ b_hh0,
    const float* __restrict__ w_hh1, const float* __restrict__ b_hh1,
    const _Float16* __restrict__ w_ih1h, const float* __restrict__ b_ih1,
    float* __restrict__ ys,          // [B][T][256] gru_out
    int* flags)                      // [B][NCH]
{
    __shared__ _Float16 hbuf[2][272];
    __shared__ _Float16 hchunk[CHUNK][264];   // 528B rows: 16B-aligned for b128
    const int tid = threadIdx.x;
    const int lane = tid & 63;
    const int wv = tid >> 6;     // wave 0..7
    const int col = lane & 15;
    const int hi = lane >> 4;
    const bool isL0 = blockIdx.x < 16;
    const int b = isL0 ? blockIdx.x : blockIdx.x - 16;

    const float* wm = isL0 ? w_hh0 : w_hh1;
    const float* bb = isL0 ? b_hh0 : b_hh1;

    // recurrent weight fragments (this thread's 2 units x 3 gates)
    f16x8 bf[3][2][8];
    float bias_[3][2];
    #pragma unroll
    for (int g = 0; g < 3; ++g) {
        #pragma unroll
        for (int q = 0; q < 2; ++q) {
            const int n = g * 256 + wv * 32 + q * 16 + col;
            bias_[g][q] = bb[n];
            #pragma unroll
            for (int c = 0; c < 8; ++c) {
                const float* src = wm + (size_t)n * 256 + c * 32 + hi * 8;
                float4 u0 = *(const float4*)(src);
                float4 u1 = *(const float4*)(src + 4);
                bf[g][q][c] = pack8(u0, u1);
            }
        }
    }
    // xp1-GEMM bias (L0 only; wave wv owns n-tiles wv*6..wv*6+5)
    float bias1_[6];
    #pragma unroll
    for (int j = 0; j < 6; ++j) bias1_[j] = b_ih1[(wv * 6 + j) * 16 + col];

    float hold[2] = {0.f, 0.f};
    if (tid < 256) hbuf[0][tid] = (_Float16)0.f;
    __syncthreads();

    float* xbase = xp + (size_t)b * T_ * G3_;
    float* ybase = ys + (size_t)b * T_ * H_;

    float pref[3][2];
    if (isL0) {
        #pragma unroll
        for (int g = 0; g < 3; ++g)
            #pragma unroll
            for (int q = 0; q < 2; ++q)
                pref[g][q] = xbase[g * 256 + wv * 32 + q * 16 + col];
    }

    int cur = 0;
    for (int c = 0; c < NCH; ++c) {
        const int t0 = c * CHUNK;
        if (!isL0) {
            // wait for xp1 chunk c from the L0 block of this batch
            if (tid == 0) {
                while (__hip_atomic_load(&flags[b * NCH + c], __ATOMIC_ACQUIRE,
                                         __HIP_MEMORY_SCOPE_AGENT) == 0) {
                    __builtin_amdgcn_s_sleep(16);
                }
                __threadfence();
            }
            __syncthreads();
            #pragma unroll
            for (int g = 0; g < 3; ++g)
                #pragma unroll
                for (int q = 0; q < 2; ++q)
                    pref[g][q] = xbase[(size_t)t0 * G3_ + g * 256 + wv * 32 + q * 16 + col];
        }
        for (int tt = 0; tt < CHUNK; ++tt) {
            const int t = t0 + tt;
            float xv[3][2];
            #pragma unroll
            for (int g = 0; g < 3; ++g)
                #pragma unroll
                for (int q = 0; q < 2; ++q)
                    xv[g][q] = pref[g][q];
            // prefetch next step (L0: global next; L1: clamp inside ready chunk)
            const int tn = isL0 ? ((t < T_ - 1) ? t + 1 : t)
                                : ((tt < CHUNK - 1) ? t + 1 : t);
            #pragma unroll
            for (int g = 0; g < 3; ++g)
                #pragma unroll
                for (int q = 0; q < 2; ++q)
                    pref[g][q] = xbase[(size_t)tn * G3_ + g * 256 + wv * 32 + q * 16 + col];

            f32x4 acc[3][2] = {};
            #pragma unroll
            for (int cc = 0; cc < 8; ++cc) {
                f16x8 a = *(const f16x8*)(&hbuf[cur][cc * 32 + hi * 8]); // broadcast A
                #pragma unroll
                for (int g = 0; g < 3; ++g)
                    #pragma unroll
                    for (int q = 0; q < 2; ++q)
                        acc[g][q] = __builtin_amdgcn_mfma_f32_16x16x32_f16(a, bf[g][q][cc], acc[g][q], 0, 0, 0);
            }

            const int nxt = cur ^ 1;
            #pragma unroll
            for (int q = 0; q < 2; ++q) {
                const int unit = wv * 32 + q * 16 + col;
                float ghr = acc[0][q][0] + bias_[0][q];
                float ghz = acc[1][q][0] + bias_[1][q];
                float ghn = acc[2][q][0] + bias_[2][q];
                float r = sigmoidf_(xv[0][q] + ghr);
                float z = sigmoidf_(xv[1][q] + ghz);
                float nn = tanh_fast(xv[2][q] + r * ghn);
                float hv = (1.f - z) * nn + z * hold[q];
                hold[q] = hv;
                if (hi == 0) {
                    hbuf[nxt][unit] = (_Float16)hv;
                    if (isL0) hchunk[tt][unit] = (_Float16)hv;
                    else      ybase[(size_t)t * H_ + unit] = hv;
                }
            }
            // raw barrier: drain LDS only; keep xp prefetch + ys stores in flight
            asm volatile("s_waitcnt lgkmcnt(0)" ::: "memory");
            __builtin_amdgcn_s_barrier();
            asm volatile("" ::: "memory");
            cur = nxt;
        }
        if (isL0) {
            // xp1 chunk GEMM: rows t0..t0+63 (hchunk f16) x w_ih1h^T -> xp (in place).
            // Low-pressure schedule: one bfr live at a time, 4 named accumulators.
            #pragma unroll
            for (int j = 0; j < 6; ++j) {
                const int n = (wv * 6 + j) * 16 + col;
                f32x4 ga0 = {}, ga1 = {}, ga2 = {}, ga3 = {};
                #pragma unroll
                for (int kk = 0; kk < 8; ++kk) {
                    f16x8 bfr = *(const f16x8*)(w_ih1h + (size_t)n * 256 + kk * 32 + hi * 8);
                    f16x8 a0 = *(const f16x8*)&hchunk[ 0 + col][kk * 32 + hi * 8];
                    f16x8 a1 = *(const f16x8*)&hchunk[16 + col][kk * 32 + hi * 8];
                    f16x8 a2 = *(const f16x8*)&hchunk[32 + col][kk * 32 + hi * 8];
                    f16x8 a3 = *(const f16x8*)&hchunk[48 + col][kk * 32 + hi * 8];
                    ga0 = __builtin_amdgcn_mfma_f32_16x16x32_f16(a0, bfr, ga0, 0, 0, 0);
                    ga1 = __builtin_amdgcn_mfma_f32_16x16x32_f16(a1, bfr, ga1, 0, 0, 0);
                    ga2 = __builtin_amdgcn_mfma_f32_16x16x32_f16(a2, bfr, ga2, 0, 0, 0);
                    ga3 = __builtin_amdgcn_mfma_f32_16x16x32_f16(a3, bfr, ga3, 0, 0, 0);
                }
                const float bv = bias1_[j];
                #pragma unroll
                for (int r = 0; r < 4; ++r) {
                    xbase[(size_t)(t0 +  0 + hi * 4 + r) * G3_ + n] = ga0[r] + bv;
                    xbase[(size_t)(t0 + 16 + hi * 4 + r) * G3_ + n] = ga1[r] + bv;
                    xbase[(size_t)(t0 + 32 + hi * 4 + r) * G3_ + n] = ga2[r] + bv;
                    xbase[(size_t)(t0 + 48 + hi * 4 + r) * G3_ + n] = ga3[r] + bv;
                }
            }
            asm volatile("s_waitcnt vmcnt(0)" ::: "memory");
            __syncthreads();
            if (tid == 0) {
                __threadfence();
                __hip_atomic_store(&flags[b * NCH + c], 1, __ATOMIC_RELEASE,
                                   __HIP_MEMORY_SCOPE_AGENT);
            }
        }
    }
}

// ---------------- prep: gat_W transpose + w_ih1 -> f16 ----------------
__global__ void gatw_t(const float* __restrict__ gw, float* __restrict__ W2)
{
    int idx = blockIdx.x * 256 + threadIdx.x;
    int n = idx >> 8, d = idx & 255;
    W2[idx] = gw[(size_t)(n >> 6) * 16384 + (size_t)d * 64 + (n & 63)];
}

__global__ void prep_wih1(const float* __restrict__ w, _Float16* __restrict__ wh)
{
    int i = (blockIdx.x * 256 + threadIdx.x) * 4; // 196608 elems
    float4 v = *(const float4*)(w + i);
    wh[i + 0] = (_Float16)v.x; wh[i + 1] = (_Float16)v.y;
    wh[i + 2] = (_Float16)v.z; wh[i + 3] = (_Float16)v.w;
}

// ---------------- e1/e2 ----------------
__global__ __launch_bounds__(256) void gat_e(
    const float* __restrict__ hk, const float* __restrict__ ga,
    float* __restrict__ e1, float* __restrict__ e2)
{
    __shared__ float tile[128][65];
    __shared__ float a1s[64], a2s[64];
    const int tt = blockIdx.x, k = blockIdx.y, b = blockIdx.z;
    const int tid = threadIdx.x;
    if (tid < 64) { a1s[tid] = ga[k * 128 + tid]; a2s[tid] = ga[k * 128 + 64 + tid]; }
    #pragma unroll
    for (int rep = 0; rep < 32; ++rep) {
        int idx = rep * 256 + tid; int tl = idx >> 6, f = idx & 63;
        tile[tl][f] = hk[((size_t)(b * 1024 + tt * 128 + tl)) * 256 + k * 64 + f];
    }
    __syncthreads();
    if (tid < 128) {
        float s1 = 0.f, s2 = 0.f;
        #pragma unroll 8
        for (int f = 0; f < 64; ++f) {
            float hv = tile[tid][f];
            s1 += hv * a1s[f]; s2 += hv * a2s[f];
        }
        const size_t o = (size_t)(b * 4 + k) * 1024 + tt * 128 + tid;
        e1[o] = s1; e2[o] = s2;
    }
}

// ---------------- GAT attention (MFMA PV, monotone-leaky exact max) ----------------
__global__ __launch_bounds__(256) void gat_attn(
    const float* __restrict__ hk, const float* __restrict__ e1,
    const float* __restrict__ e2, float* __restrict__ outp)
{
    __shared__ _Float16 hkT[64][72];
    __shared__ float e1s[64], e2s[64], lssh[64];
    __shared__ float red[4];
    const int tid = threadIdx.x;
    const int wv = tid >> 6, lane = tid & 63;
    const int col = lane & 15, hi = lane >> 4;
    const int tt = blockIdx.x, k = blockIdx.y, b = blockIdx.z;
    const int t0 = tt * 64;
    const float* e2row = e2 + (size_t)(b * 4 + k) * 1024;
    if (tid < 64) e1s[tid] = e1[(size_t)(b * 4 + k) * 1024 + t0 + tid];
    float m = -3.4e38f;
    for (int i = tid; i < 1024; i += 256) m = fmaxf(m, e2row[i]);
    #pragma unroll
    for (int off = 1; off < 64; off <<= 1) m = fmaxf(m, __shfl_xor(m, off));
    if (lane == 0) red[wv] = m;
    __syncthreads();
    const float e2max = fmaxf(fmaxf(red[0], red[1]), fmaxf(red[2], red[3]));
    const float e1A = e1s[wv * 16 + col];
    const float eAm = e1A + e2max;
    const float mA = (eAm > 0.f) ? eAm : 0.2f * eAm;

    float lsum = 0.f;
    f32x4 oacc[4] = {};
    const int vs = tid & 63, vfblk = (tid >> 6) * 16;
    for (int st = 0; st < 16; ++st) {
        {
            const float* hp = hk + ((size_t)(b * 1024 + st * 64 + vs)) * 256 + k * 64 + vfblk;
            float4 v0 = *(const float4*)hp, v1 = *(const float4*)(hp + 4);
            float4 v2 = *(const float4*)(hp + 8), v3 = *(const float4*)(hp + 12);
            float vv[16] = {v0.x, v0.y, v0.z, v0.w, v1.x, v1.y, v1.z, v1.w,
                            v2.x, v2.y, v2.z, v2.w, v3.x, v3.y, v3.z, v3.w};
            #pragma unroll
            for (int i = 0; i < 16; ++i) hkT[vfblk + i][vs] = (_Float16)vv[i];
        }
        if (tid < 64) e2s[tid] = e2row[st * 64 + tid];
        __syncthreads();
        #pragma unroll
        for (int c = 0; c < 2; ++c) {
            f16x8 af;
            #pragma unroll
            for (int i = 0; i < 8; ++i) {
                float e = e1A + e2s[c * 32 + hi * 8 + i];
                e = (e > 0.f) ? e : 0.2f * e;
                float pv = __expf(e - mA);
                _Float16 p16 = (_Float16)pv;
                af[i] = p16;
                lsum += (float)p16;
            }
            #pragma unroll
            for (int j = 0; j < 4; ++j) {
                f16x8 bfr = *(const f16x8*)&hkT[j * 16 + col][c * 32 + hi * 8];
                oacc[j] = __builtin_amdgcn_mfma_f32_16x16x32_f16(af, bfr, oacc[j], 0, 0, 0);
            }
        }
        __syncthreads();
    }
    lsum += __shfl_xor(lsum, 16);
    lsum += __shfl_xor(lsum, 32);
    if (hi == 0) lssh[wv * 16 + col] = lsum;
    #pragma unroll
    for (int r = 0; r < 4; ++r) {
        const float inv = 1.f / lssh[wv * 16 + hi * 4 + r];
        #pragma unroll
        for (int j = 0; j < 4; ++j)
            outp[((size_t)(b * 1024 + t0 + wv * 16 + hi * 4 + r)) * 256 + k * 64 + j * 16 + col]
                = oacc[j][r] * inv;
    }
}

// ---------------- residual + LayerNorm ----------------
__global__ __launch_bounds__(64) void add_ln(
    const float* __restrict__ a, const float* bb,
    const float* __restrict__ gamma, const float* __restrict__ beta,
    float* outp)
{
    const int row = blockIdx.x;
    const int lane = threadIdx.x;
    const size_t base = (size_t)row * 256 + lane * 4;
    float4 va = *(const float4*)(a + base);
    float4 vb = *(const float4*)(bb + base);
    float xv[4] = {va.x + vb.x, va.y + vb.y, va.z + vb.z, va.w + vb.w};
    float s = xv[0] + xv[1] + xv[2] + xv[3];
    float s2 = xv[0] * xv[0] + xv[1] * xv[1] + xv[2] * xv[2] + xv[3] * xv[3];
    #pragma unroll
    for (int off = 32; off >= 1; off >>= 1) {
        s += __shfl_xor(s, off);
        s2 += __shfl_xor(s2, off);
    }
    const float mu = s * (1.f / 256.f);
    const float var = s2 * (1.f / 256.f) - mu * mu;
    const float rs = rsqrtf(var + 1e-5f);
    float4 g4 = *(const float4*)(gamma + lane * 4);
    float4 b4 = *(const float4*)(beta + lane * 4);
    float4 ov;
    ov.x = (xv[0] - mu) * rs * g4.x + b4.x;
    ov.y = (xv[1] - mu) * rs * g4.y + b4.y;
    ov.z = (xv[2] - mu) * rs * g4.z + b4.z;
    ov.w = (xv[3] - mu) * rs * g4.w + b4.w;
    *(float4*)(outp + base) = ov;
}

// ---------------- MHA flash attention (MFMA QK^T + PV) ----------------
__global__ __launch_bounds__(256) void mha_attn(const float* __restrict__ qkv, float* __restrict__ o)
{
    __shared__ _Float16 ks[64][72];
    __shared__ _Float16 vts[64][72];
    __shared__ _Float16 ps[64][72];
    const int tid = threadIdx.x;
    const int wv = tid >> 6, lane = tid & 63;
    const int col = lane & 15, hi = lane >> 4;
    const int tt = blockIdx.x, h = blockIdx.y, b = blockIdx.z;
    const int t0 = tt * 64;
    const float* base = qkv + (size_t)b * 1024 * 768;

    f16x8 qf[2];
    #pragma unroll
    for (int c = 0; c < 2; ++c) {
        const float* src = base + (size_t)(t0 + wv * 16 + col) * 768 + h * 64 + c * 32 + hi * 8;
        float4 u0 = *(const float4*)src, u1 = *(const float4*)(src + 4);
        u0.x *= 0.125f; u0.y *= 0.125f; u0.z *= 0.125f; u0.w *= 0.125f;
        u1.x *= 0.125f; u1.y *= 0.125f; u1.z *= 0.125f; u1.w *= 0.125f;
        qf[c] = pack8(u0, u1);
    }
    f32x4 oacc[4] = {};
    float mrow[4] = {-3.4e38f, -3.4e38f, -3.4e38f, -3.4e38f};
    float lrow[4] = {};
    const int srow = tid >> 2, sdblk = (tid & 3) * 16;
    const int vs = tid & 63, vdblk = (tid >> 6) * 16;

    for (int st = 0; st < 16; ++st) {
        {
            const float* kp = base + (size_t)(st * 64 + srow) * 768 + 256 + h * 64 + sdblk;
            float4 k0 = *(const float4*)kp, k1 = *(const float4*)(kp + 4);
            float4 k2 = *(const float4*)(kp + 8), k3 = *(const float4*)(kp + 12);
            *(f16x8*)&ks[srow][sdblk] = pack8(k0, k1);
            *(f16x8*)&ks[srow][sdblk + 8] = pack8(k2, k3);
            const float* vp = base + (size_t)(st * 64 + vs) * 768 + 512 + h * 64 + vdblk;
            float4 v0 = *(const float4*)vp, v1 = *(const float4*)(vp + 4);
            float4 v2 = *(const float4*)(vp + 8), v3 = *(const float4*)(vp + 12);
            float vv[16] = {v0.x, v0.y, v0.z, v0.w, v1.x, v1.y, v1.z, v1.w,
                            v2.x, v2.y, v2.z, v2.w, v3.x, v3.y, v3.z, v3.w};
            #pragma unroll
            for (int i = 0; i < 16; ++i) vts[vdblk + i][vs] = (_Float16)vv[i];
        }
        __syncthreads();
        f32x4 sacc[4] = {};
        #pragma unroll
        for (int c = 0; c < 2; ++c) {
            #pragma unroll
            for (int j = 0; j < 4; ++j) {
                f16x8 bfr = *(const f16x8*)&ks[j * 16 + col][c * 32 + hi * 8];
                sacc[j] = __builtin_amdgcn_mfma_f32_16x16x32_f16(qf[c], bfr, sacc[j], 0, 0, 0);
            }
        }
        #pragma unroll
        for (int r = 0; r < 4; ++r) {
            float tm = fmaxf(fmaxf(sacc[0][r], sacc[1][r]), fmaxf(sacc[2][r], sacc[3][r]));
            tm = fmaxf(tm, __shfl_xor(tm, 1));
            tm = fmaxf(tm, __shfl_xor(tm, 2));
            tm = fmaxf(tm, __shfl_xor(tm, 4));
            tm = fmaxf(tm, __shfl_xor(tm, 8));
            const float mn = fmaxf(mrow[r], tm);
            const float corr = __expf(mrow[r] - mn);
            mrow[r] = mn;
            float lsum = 0.f;
            #pragma unroll
            for (int j = 0; j < 4; ++j) {
                float pv = __expf(sacc[j][r] - mn);
                _Float16 p16 = (_Float16)pv;
                ps[wv * 16 + hi * 4 + r][j * 16 + col] = p16;
                lsum += (float)p16;
            }
            lsum += __shfl_xor(lsum, 1);
            lsum += __shfl_xor(lsum, 2);
            lsum += __shfl_xor(lsum, 4);
            lsum += __shfl_xor(lsum, 8);
            lrow[r] = lrow[r] * corr + lsum;
            #pragma unroll
            for (int j = 0; j < 4; ++j) oacc[j][r] *= corr;
        }
        #pragma unroll
        for (int c = 0; c < 2; ++c) {
            f16x8 a = *(const f16x8*)&ps[wv * 16 + col][c * 32 + hi * 8];
            #pragma unroll
            for (int j = 0; j < 4; ++j) {
                f16x8 bfr = *(const f16x8*)&vts[j * 16 + col][c * 32 + hi * 8];
                oacc[j] = __builtin_amdgcn_mfma_f32_16x16x32_f16(a, bfr, oacc[j], 0, 0, 0);
            }
        }
        __syncthreads();
    }
    float inv[4];
    #pragma unroll
    for (int r = 0; r < 4; ++r) inv[r] = 1.f / lrow[r];
    #pragma unroll
    for (int j = 0; j < 4; ++j)
        #pragma unroll
        for (int r = 0; r < 4; ++r)
            o[((size_t)(b * 1024 + t0 + wv * 16 + hi * 4 + r)) * 256 + h * 64 + j * 16 + col]
                = oacc[j][r] * inv[r];
}

// ---------------- mean over T ----------------
__global__ __launch_bounds__(256) void pool_mean(const float* __restrict__ o, float* __restrict__ opool)
{
    const int b = blockIdx.x >> 3, chunk = blockIdx.x & 7;
    const int d = threadIdx.x;
    float s = 0.f;
    for (int t = chunk * 128; t < chunk * 128 + 128; ++t)
        s += o[((size_t)(b * 1024 + t)) * 256 + d];
    atomicAdd(&opool[b * 256 + d], s * (1.f / 1024.f));
}

// ---------------- head ----------------
__global__ __launch_bounds__(256) void head_k(
    const float* __restrict__ opool, const float* __restrict__ wout, const float* __restrict__ bout,
    const float* __restrict__ f1w, const float* __restrict__ f1b,
    const float* __restrict__ f2w, const float* __restrict__ f2b,
    float* __restrict__ outp)
{
    __shared__ float op[256], pooled[256], hid[128];
    const int b = blockIdx.x, e = threadIdx.x;
    op[e] = opool[b * 256 + e];
    __syncthreads();
    float s = bout[e];
    for (int d = 0; d < 256; d += 4) {
        float4 w4 = *(const float4*)(wout + (size_t)e * 256 + d);
        s += op[d] * w4.x + op[d + 1] * w4.y + op[d + 2] * w4.z + op[d + 3] * w4.w;
    }
    pooled[e] = s;
    __syncthreads();
    if (e < 128) {
        float s2 = f1b[e];
        for (int d = 0; d < 256; d += 4) {
            float4 w4 = *(const float4*)(f1w + (size_t)e * 256 + d);
            s2 += pooled[d] * w4.x + pooled[d + 1] * w4.y + pooled[d + 2] * w4.z + pooled[d + 3] * w4.w;
        }
        hid[e] = fmaxf(s2, 0.f);
    }
    __syncthreads();
    if (e < 2) {
        float s3 = f2b[e];
        for (int j = 0; j < 128; ++j) s3 += hid[j] * f2w[e * 128 + j];
        outp[b * 2 + e] = s3;
    }
}

extern "C" void kernel_launch(void* const* d_in, const int* in_sizes, int n_in,
                              void* d_out, int out_size, void* d_ws, size_t ws_size,
                              hipStream_t stream)
{
    const float* x         = (const float*)d_in[0];
    const float* w_ih0     = (const float*)d_in[1];
    const float* w_hh0     = (const float*)d_in[2];
    const float* b_ih0     = (const float*)d_in[3];
    const float* b_hh0     = (const float*)d_in[4];
    const float* w_ih1     = (const float*)d_in[5];
    const float* w_hh1     = (const float*)d_in[6];
    const float* b_ih1     = (const float*)d_in[7];
    const float* b_hh1     = (const float*)d_in[8];
    const float* gat_W     = (const float*)d_in[9];
    const float* gat_a     = (const float*)d_in[10];
    const float* ln_g      = (const float*)d_in[11];
    const float* ln_b      = (const float*)d_in[12];
    const float* mha_in_w  = (const float*)d_in[13];
    const float* mha_in_b  = (const float*)d_in[14];
    const float* mha_out_w = (const float*)d_in[15];
    const float* mha_out_b = (const float*)d_in[16];
    const float* fc1_w     = (const float*)d_in[17];
    const float* fc1_b     = (const float*)d_in[18];
    const float* fc2_w     = (const float*)d_in[19];
    const float* fc2_b     = (const float*)d_in[20];
    float* out = (float*)d_out;

    float* xpbuf = (float*)d_ws;                       // [B*T][768] xp0 -> xp1 (in place)
    float* buf1  = xpbuf + (size_t)B_ * T_ * G3_;      // [B*T][256] (gat / h)
    float* buf2  = buf1 + (size_t)B_ * T_ * H_;        // [B*T][256] (gru_out)
    float* buf3  = buf2 + (size_t)B_ * T_ * H_;        // [B*T][256] (hk / o)
    float* W2    = buf3 + (size_t)B_ * T_ * H_;        // 65536
    float* e1    = W2 + 65536;
    float* e2    = e1 + 65536;
    float* opool = e2 + 65536;                         // 4096 floats
    int*   flags = (int*)(opool + 4096);               // 256 ints
    _Float16* wih1h = (_Float16*)(flags + 256);        // 196608 f16

    dim3 blk(256);
    gatw_t<<<dim3(256), blk, 0, stream>>>(gat_W, W2);
    prep_wih1<<<dim3(192), blk, 0, stream>>>(w_ih1, wih1h);
    // xp0 = x @ w_ih0^T + b_ih0   (M=B*T, N=G3, K=IN)
    gemm16<<<dim3(G3_ / 64, (B_ * T_) / 64), blk, 0, stream>>>(x, w_ih0, b_ih0, xpbuf, B_ * T_, G3_, IN_);
    // zero opool + flags (single contiguous region)
    hipMemsetAsync(opool, 0, 4096 * sizeof(float) + 256 * sizeof(int), stream);
    // fused pipelined scans: L0 (blocks 0-15) -> xp1 in place -> L1 (blocks 16-31) -> buf2
    fused_gru<<<dim3(32), dim3(512), 0, stream>>>(xpbuf, w_hh0, b_hh0, w_hh1, b_hh1,
                                                  wih1h, b_ih1, buf2, flags);
    // hk = gru_out @ W2^T -> buf3   (M=B*T, N=H, K=H)
    gemm16<<<dim3(H_ / 64, (B_ * T_) / 64), blk, 0, stream>>>(buf2, W2, nullptr, buf3, B_ * T_, H_, H_);
    gat_e<<<dim3(8, 4, 16), blk, 0, stream>>>(buf3, gat_a, e1, e2);
    gat_attn<<<dim3(16, 4, 16), blk, 0, stream>>>(buf3, e1, e2, buf1);
    add_ln<<<dim3(B_ * T_), dim3(64), 0, stream>>>(buf2, buf1, ln_g, ln_b, buf1);
    // qkv = h @ mha_in_w^T + b -> xpbuf   (M=B*T, N=G3, K=H)
    gemm16<<<dim3(G3_ / 64, (B_ * T_) / 64), blk, 0, stream>>>(buf1, mha_in_w, mha_in_b, xpbuf, B_ * T_, G3_, H_);
    mha_attn<<<dim3(16, 4, 16), blk, 0, stream>>>(xpbuf, buf3);
    pool_mean<<<dim3(128), blk, 0, stream>>>(buf3, opool);
    head_k<<<dim3(16), blk, 0, stream>>>(opool, mha_out_w, mha_out_b, fc1_w, fc1_b, fc2_w, fc2_b, out);
}

// Round 14
// 1577.391 us; speedup vs baseline: 1.8431x; 1.1908x over previous
//
#include <hip/hip_runtime.h>
#include <hip/hip_bf16.h>

// GNNClassifier: 2x GRU(scan, 3-stage pipelined) -> GAT -> LN -> MHA -> pool -> FC
// B=16 T=1024 IN=64 H=256 G3=768 K=4 F=64 NH=4 HD=64 C=2
// Round-14: resurrect round-7's 3-stage fused_gru (L0 scan -> G xp1-gemm -> L1
// scan; 48 blocks). Rounds 7-11 failures were proven (round 11/12) to be a
// LAUNCHER bug (qkv gemm16 N=256 instead of 768), not this kernel. The 3-stage
// topology removes the ~31us/chunk serial GEMM from L0's critical path
// (round-13 measured: scan 66us/chunk + GEMM 31us/chunk serial = 1660us).
// Steady-state rate becomes max(66, ~30, 66) = 66us/chunk.

#define B_ 16
#define T_ 1024
#define IN_ 64
#define H_ 256
#define G3_ 768
#define CHUNK 64
#define NCH (T_ / CHUNK)

typedef _Float16 f16x8 __attribute__((ext_vector_type(8)));
typedef float f32x4 __attribute__((ext_vector_type(4)));

__device__ __forceinline__ float fastrcp(float x) { return __builtin_amdgcn_rcpf(x); }
__device__ __forceinline__ float sigmoidf_(float x) { return fastrcp(1.f + __expf(-x)); }
__device__ __forceinline__ float tanh_fast(float x) {
    float t = __expf(-2.f * fabsf(x));
    float r = (1.f - t) * fastrcp(1.f + t);
    return x >= 0.f ? r : -r;
}

__device__ __forceinline__ f16x8 pack8(float4 a, float4 b) {
    f16x8 v;
    v[0] = (_Float16)a.x; v[1] = (_Float16)a.y; v[2] = (_Float16)a.z; v[3] = (_Float16)a.w;
    v[4] = (_Float16)b.x; v[5] = (_Float16)b.y; v[6] = (_Float16)b.z; v[7] = (_Float16)b.w;
    return v;
}

// ---------------- f16-MFMA tiled GEMM: Y[M][N] = X[M][Kd] @ W[N][Kd]^T + bias ----------------
__global__ __launch_bounds__(256) void gemm16(
    const float* __restrict__ X, const float* __restrict__ W,
    const float* __restrict__ bias, float* __restrict__ Y,
    int M, int N, int Kd)
{
    __shared__ _Float16 As[2][64][40];
    __shared__ _Float16 Bs[2][64][40];
    const int tid = threadIdx.x;
    const int wv = tid >> 6, lane = tid & 63;
    const int col = lane & 15, hi = lane >> 4;
    const int bm = blockIdx.y * 64, bn = blockIdx.x * 64;
    const int srow = tid >> 2, scol = (tid & 3) * 8;
    const float* xrow = X + (size_t)(bm + srow) * Kd + scol;
    const float* wrow = W + (size_t)(bn + srow) * Kd + scol;
    const int nk = Kd >> 5;

    {
        float4 a0 = *(const float4*)(xrow);
        float4 a1 = *(const float4*)(xrow + 4);
        float4 b0 = *(const float4*)(wrow);
        float4 b1 = *(const float4*)(wrow + 4);
        *(f16x8*)&As[0][srow][scol] = pack8(a0, a1);
        *(f16x8*)&Bs[0][srow][scol] = pack8(b0, b1);
    }
    __syncthreads();
    f32x4 acc[4] = {};
    for (int kc = 0; kc < nk; ++kc) {
        const int cur = kc & 1;
        f16x8 va, vb;
        const bool have = (kc + 1 < nk);
        if (have) {
            const float* xa = xrow + (kc + 1) * 32;
            const float* wa = wrow + (kc + 1) * 32;
            float4 a0 = *(const float4*)xa, a1 = *(const float4*)(xa + 4);
            float4 b0 = *(const float4*)wa, b1 = *(const float4*)(wa + 4);
            va = pack8(a0, a1);
            vb = pack8(b0, b1);
        }
        f16x8 a = *(const f16x8*)&As[cur][wv * 16 + col][hi * 8];
        #pragma unroll
        for (int j = 0; j < 4; ++j) {
            f16x8 bfr = *(const f16x8*)&Bs[cur][j * 16 + col][hi * 8];
            acc[j] = __builtin_amdgcn_mfma_f32_16x16x32_f16(a, bfr, acc[j], 0, 0, 0);
        }
        if (have) {
            *(f16x8*)&As[cur ^ 1][srow][scol] = va;
            *(f16x8*)&Bs[cur ^ 1][srow][scol] = vb;
        }
        __syncthreads();
    }
    #pragma unroll
    for (int j = 0; j < 4; ++j) {
        const int n = bn + j * 16 + col;
        const float bv = bias ? bias[n] : 0.f;
        #pragma unroll
        for (int r = 0; r < 4; ++r) {
            const int m = bm + wv * 16 + hi * 4 + r;
            Y[(size_t)m * N + n] = acc[j][r] + bv;
        }
    }
}

// ---------------- fused 3-stage pipelined GRU ----------------
// 48 blocks: role = blockIdx.x>>4 (0=L0 scan, 1=G xp1-gemm, 2=L1 scan), b = blockIdx.x&15.
// L0: scans layer 0; streams h1 (f16, coalesced) to h1b; per chunk releases flagA[b][c].
// G : waits flagA[b][c]; xp1 chunk = h1 @ w_ih1^T + b_ih1 written IN PLACE over the
//     consumed xp0 chunk (safe: every L0 read of element s happens at steps s-1/s,
//     strictly before flagA[chunk(s)] is released); releases flagB[b][c].
// L1: waits flagB[b][c]; scans layer 1 chunk; writes gru_out.
// Chain is one-directional & monotone -> deadlock-free; 48 blocks co-resident.
// Same fence/flag pattern as the twice-verified (r6/r13) 2-stage handoff.
__global__ __launch_bounds__(512, 2) void fused_gru(
    float* xp,                        // [B][T][768] xp0 in, overwritten by xp1 per chunk
    const float* __restrict__ w_hh0, const float* __restrict__ b_hh0,
    const float* __restrict__ w_hh1, const float* __restrict__ b_hh1,
    const _Float16* __restrict__ w_ih1h, const float* __restrict__ b_ih1,
    _Float16* h1b,                    // [B][T][256] f16 (layer-0 output stream)
    float* __restrict__ ys,           // [B][T][256] gru_out
    int* flags)                       // [0..255]=flagA[b][c], [256..511]=flagB[b][c]
{
    __shared__ _Float16 hbuf[2][272];
    const int tid = threadIdx.x;
    const int lane = tid & 63;
    const int wv = tid >> 6;
    const int col = lane & 15;
    const int hi = lane >> 4;
    const int role = blockIdx.x >> 4;
    const int b = blockIdx.x & 15;

    if (role == 1) {
        // ---- G: xp1 chunk GEMM (M=64 rows x N=768), 8 waves: mt=wv&3, jbase=(wv>>2)*24
        const int mt = wv & 3;
        const int jbase = (wv >> 2) * 24;
        float* xbase = xp + (size_t)b * T_ * G3_;
        const _Float16* hbase = h1b + (size_t)b * T_ * H_;
        for (int c = 0; c < NCH; ++c) {
            const int t0 = c * CHUNK;
            if (tid == 0) {
                while (__hip_atomic_load(&flags[b * NCH + c], __ATOMIC_ACQUIRE,
                                         __HIP_MEMORY_SCOPE_AGENT) == 0)
                    __builtin_amdgcn_s_sleep(8);
                __threadfence();
            }
            __syncthreads();
            f16x8 af[8];
            #pragma unroll
            for (int kk = 0; kk < 8; ++kk)
                af[kk] = *(const f16x8*)(hbase + (size_t)(t0 + mt * 16 + col) * H_ + kk * 32 + hi * 8);
            for (int j = 0; j < 24; ++j) {
                const int n = (jbase + j) * 16 + col;
                f16x8 bfr[8];
                #pragma unroll
                for (int kk = 0; kk < 8; ++kk)
                    bfr[kk] = *(const f16x8*)(w_ih1h + (size_t)n * 256 + kk * 32 + hi * 8);
                f32x4 ga = {};
                #pragma unroll
                for (int kk = 0; kk < 8; ++kk)
                    ga = __builtin_amdgcn_mfma_f32_16x16x32_f16(af[kk], bfr[kk], ga, 0, 0, 0);
                const float bv = b_ih1[n];
                #pragma unroll
                for (int r = 0; r < 4; ++r)
                    xbase[(size_t)(t0 + mt * 16 + hi * 4 + r) * G3_ + n] = ga[r] + bv;
            }
            asm volatile("s_waitcnt vmcnt(0)" ::: "memory");
            __syncthreads();
            if (tid == 0) {
                __threadfence();
                __hip_atomic_store(&flags[256 + b * NCH + c], 1, __ATOMIC_RELEASE,
                                   __HIP_MEMORY_SCOPE_AGENT);
            }
        }
        return;
    }

    // ---- scan path (L0 or L1) ----
    const bool isL0 = (role == 0);
    const float* wm = isL0 ? w_hh0 : w_hh1;
    const float* bbp = isL0 ? b_hh0 : b_hh1;

    f16x8 bf[3][2][8];
    float bias_[3][2];
    #pragma unroll
    for (int g = 0; g < 3; ++g) {
        #pragma unroll
        for (int q = 0; q < 2; ++q) {
            const int n = g * 256 + wv * 32 + q * 16 + col;
            bias_[g][q] = bbp[n];
            #pragma unroll
            for (int c = 0; c < 8; ++c) {
                const float* src = wm + (size_t)n * 256 + c * 32 + hi * 8;
                float4 u0 = *(const float4*)(src);
                float4 u1 = *(const float4*)(src + 4);
                bf[g][q][c] = pack8(u0, u1);
            }
        }
    }
    float hold[2] = {0.f, 0.f};
    if (tid < 256) hbuf[0][tid] = (_Float16)0.f;
    __syncthreads();

    float* xbase = xp + (size_t)b * T_ * G3_;
    float* ybase = ys + (size_t)b * T_ * H_;
    _Float16* hbase = h1b + (size_t)b * T_ * H_;

    float pref[3][2];
    if (isL0) {
        #pragma unroll
        for (int g = 0; g < 3; ++g)
            #pragma unroll
            for (int q = 0; q < 2; ++q)
                pref[g][q] = xbase[g * 256 + wv * 32 + q * 16 + col];
    }

    int cur = 0;
    for (int c = 0; c < NCH; ++c) {
        const int t0 = c * CHUNK;
        if (!isL0) {
            if (tid == 0) {
                while (__hip_atomic_load(&flags[256 + b * NCH + c], __ATOMIC_ACQUIRE,
                                         __HIP_MEMORY_SCOPE_AGENT) == 0)
                    __builtin_amdgcn_s_sleep(8);
                __threadfence();
            }
            __syncthreads();
            #pragma unroll
            for (int g = 0; g < 3; ++g)
                #pragma unroll
                for (int q = 0; q < 2; ++q)
                    pref[g][q] = xbase[(size_t)t0 * G3_ + g * 256 + wv * 32 + q * 16 + col];
        }
        for (int tt = 0; tt < CHUNK; ++tt) {
            const int t = t0 + tt;
            float xv[3][2];
            #pragma unroll
            for (int g = 0; g < 3; ++g)
                #pragma unroll
                for (int q = 0; q < 2; ++q)
                    xv[g][q] = pref[g][q];
            // prefetch next step (L0: global next; L1: clamp inside ready chunk)
            const int tn = isL0 ? ((t < T_ - 1) ? t + 1 : t)
                                : ((tt < CHUNK - 1) ? t + 1 : t);
            #pragma unroll
            for (int g = 0; g < 3; ++g)
                #pragma unroll
                for (int q = 0; q < 2; ++q)
                    pref[g][q] = xbase[(size_t)tn * G3_ + g * 256 + wv * 32 + q * 16 + col];

            f32x4 acc[3][2] = {};
            #pragma unroll
            for (int cc = 0; cc < 8; ++cc) {
                f16x8 a = *(const f16x8*)(&hbuf[cur][cc * 32 + hi * 8]); // broadcast A
                #pragma unroll
                for (int g = 0; g < 3; ++g)
                    #pragma unroll
                    for (int q = 0; q < 2; ++q)
                        acc[g][q] = __builtin_amdgcn_mfma_f32_16x16x32_f16(a, bf[g][q][cc], acc[g][q], 0, 0, 0);
            }

            const int nxt = cur ^ 1;
            #pragma unroll
            for (int q = 0; q < 2; ++q) {
                const int unit = wv * 32 + q * 16 + col;
                float ghr = acc[0][q][0] + bias_[0][q];
                float ghz = acc[1][q][0] + bias_[1][q];
                float ghn = acc[2][q][0] + bias_[2][q];
                float r = sigmoidf_(xv[0][q] + ghr);
                float z = sigmoidf_(xv[1][q] + ghz);
                float nn = tanh_fast(xv[2][q] + r * ghn);
                float hv = (1.f - z) * nn + z * hold[q];
                hold[q] = hv;
                if (hi == 0) {
                    _Float16 h16 = (_Float16)hv;
                    hbuf[nxt][unit] = h16;
                    if (isL0) hbase[(size_t)t * H_ + unit] = h16;   // coalesced f16 stream
                    else      ybase[(size_t)t * H_ + unit] = hv;
                }
            }
            // raw barrier: drain LDS only; keep xp prefetch + stores in flight
            asm volatile("s_waitcnt lgkmcnt(0)" ::: "memory");
            __builtin_amdgcn_s_barrier();
            asm volatile("" ::: "memory");
            cur = nxt;
        }
        if (isL0) {
            asm volatile("s_waitcnt vmcnt(0)" ::: "memory");
            __syncthreads();
            if (tid == 0) {
                __threadfence();
                __hip_atomic_store(&flags[b * NCH + c], 1, __ATOMIC_RELEASE,
                                   __HIP_MEMORY_SCOPE_AGENT);
            }
        }
    }
}

// ---------------- prep: gat_W transpose + w_ih1 -> f16 ----------------
__global__ void gatw_t(const float* __restrict__ gw, float* __restrict__ W2)
{
    int idx = blockIdx.x * 256 + threadIdx.x;
    int n = idx >> 8, d = idx & 255;
    W2[idx] = gw[(size_t)(n >> 6) * 16384 + (size_t)d * 64 + (n & 63)];
}

__global__ void prep_wih1(const float* __restrict__ w, _Float16* __restrict__ wh)
{
    int i = (blockIdx.x * 256 + threadIdx.x) * 4; // 196608 elems
    float4 v = *(const float4*)(w + i);
    wh[i + 0] = (_Float16)v.x; wh[i + 1] = (_Float16)v.y;
    wh[i + 2] = (_Float16)v.z; wh[i + 3] = (_Float16)v.w;
}

// ---------------- e1/e2 ----------------
__global__ __launch_bounds__(256) void gat_e(
    const float* __restrict__ hk, const float* __restrict__ ga,
    float* __restrict__ e1, float* __restrict__ e2)
{
    __shared__ float tile[128][65];
    __shared__ float a1s[64], a2s[64];
    const int tt = blockIdx.x, k = blockIdx.y, b = blockIdx.z;
    const int tid = threadIdx.x;
    if (tid < 64) { a1s[tid] = ga[k * 128 + tid]; a2s[tid] = ga[k * 128 + 64 + tid]; }
    #pragma unroll
    for (int rep = 0; rep < 32; ++rep) {
        int idx = rep * 256 + tid; int tl = idx >> 6, f = idx & 63;
        tile[tl][f] = hk[((size_t)(b * 1024 + tt * 128 + tl)) * 256 + k * 64 + f];
    }
    __syncthreads();
    if (tid < 128) {
        float s1 = 0.f, s2 = 0.f;
        #pragma unroll 8
        for (int f = 0; f < 64; ++f) {
            float hv = tile[tid][f];
            s1 += hv * a1s[f]; s2 += hv * a2s[f];
        }
        const size_t o = (size_t)(b * 4 + k) * 1024 + tt * 128 + tid;
        e1[o] = s1; e2[o] = s2;
    }
}

// ---------------- GAT attention (MFMA PV, monotone-leaky exact max) ----------------
__global__ __launch_bounds__(256) void gat_attn(
    const float* __restrict__ hk, const float* __restrict__ e1,
    const float* __restrict__ e2, float* __restrict__ outp)
{
    __shared__ _Float16 hkT[64][72];
    __shared__ float e1s[64], e2s[64], lssh[64];
    __shared__ float red[4];
    const int tid = threadIdx.x;
    const int wv = tid >> 6, lane = tid & 63;
    const int col = lane & 15, hi = lane >> 4;
    const int tt = blockIdx.x, k = blockIdx.y, b = blockIdx.z;
    const int t0 = tt * 64;
    const float* e2row = e2 + (size_t)(b * 4 + k) * 1024;
    if (tid < 64) e1s[tid] = e1[(size_t)(b * 4 + k) * 1024 + t0 + tid];
    float m = -3.4e38f;
    for (int i = tid; i < 1024; i += 256) m = fmaxf(m, e2row[i]);
    #pragma unroll
    for (int off = 1; off < 64; off <<= 1) m = fmaxf(m, __shfl_xor(m, off));
    if (lane == 0) red[wv] = m;
    __syncthreads();
    const float e2max = fmaxf(fmaxf(red[0], red[1]), fmaxf(red[2], red[3]));
    const float e1A = e1s[wv * 16 + col];
    const float eAm = e1A + e2max;
    const float mA = (eAm > 0.f) ? eAm : 0.2f * eAm;

    float lsum = 0.f;
    f32x4 oacc[4] = {};
    const int vs = tid & 63, vfblk = (tid >> 6) * 16;
    for (int st = 0; st < 16; ++st) {
        {
            const float* hp = hk + ((size_t)(b * 1024 + st * 64 + vs)) * 256 + k * 64 + vfblk;
            float4 v0 = *(const float4*)hp, v1 = *(const float4*)(hp + 4);
            float4 v2 = *(const float4*)(hp + 8), v3 = *(const float4*)(hp + 12);
            float vv[16] = {v0.x, v0.y, v0.z, v0.w, v1.x, v1.y, v1.z, v1.w,
                            v2.x, v2.y, v2.z, v2.w, v3.x, v3.y, v3.z, v3.w};
            #pragma unroll
            for (int i = 0; i < 16; ++i) hkT[vfblk + i][vs] = (_Float16)vv[i];
        }
        if (tid < 64) e2s[tid] = e2row[st * 64 + tid];
        __syncthreads();
        #pragma unroll
        for (int c = 0; c < 2; ++c) {
            f16x8 af;
            #pragma unroll
            for (int i = 0; i < 8; ++i) {
                float e = e1A + e2s[c * 32 + hi * 8 + i];
                e = (e > 0.f) ? e : 0.2f * e;
                float pv = __expf(e - mA);
                _Float16 p16 = (_Float16)pv;
                af[i] = p16;
                lsum += (float)p16;
            }
            #pragma unroll
            for (int j = 0; j < 4; ++j) {
                f16x8 bfr = *(const f16x8*)&hkT[j * 16 + col][c * 32 + hi * 8];
                oacc[j] = __builtin_amdgcn_mfma_f32_16x16x32_f16(af, bfr, oacc[j], 0, 0, 0);
            }
        }
        __syncthreads();
    }
    lsum += __shfl_xor(lsum, 16);
    lsum += __shfl_xor(lsum, 32);
    if (hi == 0) lssh[wv * 16 + col] = lsum;
    #pragma unroll
    for (int r = 0; r < 4; ++r) {
        const float inv = 1.f / lssh[wv * 16 + hi * 4 + r];
        #pragma unroll
        for (int j = 0; j < 4; ++j)
            outp[((size_t)(b * 1024 + t0 + wv * 16 + hi * 4 + r)) * 256 + k * 64 + j * 16 + col]
                = oacc[j][r] * inv;
    }
}

// ---------------- residual + LayerNorm ----------------
__global__ __launch_bounds__(64) void add_ln(
    const float* __restrict__ a, const float* bb,
    const float* __restrict__ gamma, const float* __restrict__ beta,
    float* outp)
{
    const int row = blockIdx.x;
    const int lane = threadIdx.x;
    const size_t base = (size_t)row * 256 + lane * 4;
    float4 va = *(const float4*)(a + base);
    float4 vb = *(const float4*)(bb + base);
    float xv[4] = {va.x + vb.x, va.y + vb.y, va.z + vb.z, va.w + vb.w};
    float s = xv[0] + xv[1] + xv[2] + xv[3];
    float s2 = xv[0] * xv[0] + xv[1] * xv[1] + xv[2] * xv[2] + xv[3] * xv[3];
    #pragma unroll
    for (int off = 32; off >= 1; off >>= 1) {
        s += __shfl_xor(s, off);
        s2 += __shfl_xor(s2, off);
    }
    const float mu = s * (1.f / 256.f);
    const float var = s2 * (1.f / 256.f) - mu * mu;
    const float rs = rsqrtf(var + 1e-5f);
    float4 g4 = *(const float4*)(gamma + lane * 4);
    float4 b4 = *(const float4*)(beta + lane * 4);
    float4 ov;
    ov.x = (xv[0] - mu) * rs * g4.x + b4.x;
    ov.y = (xv[1] - mu) * rs * g4.y + b4.y;
    ov.z = (xv[2] - mu) * rs * g4.z + b4.z;
    ov.w = (xv[3] - mu) * rs * g4.w + b4.w;
    *(float4*)(outp + base) = ov;
}

// ---------------- MHA flash attention (MFMA QK^T + PV) ----------------
__global__ __launch_bounds__(256) void mha_attn(const float* __restrict__ qkv, float* __restrict__ o)
{
    __shared__ _Float16 ks[64][72];
    __shared__ _Float16 vts[64][72];
    __shared__ _Float16 ps[64][72];
    const int tid = threadIdx.x;
    const int wv = tid >> 6, lane = tid & 63;
    const int col = lane & 15, hi = lane >> 4;
    const int tt = blockIdx.x, h = blockIdx.y, b = blockIdx.z;
    const int t0 = tt * 64;
    const float* base = qkv + (size_t)b * 1024 * 768;

    f16x8 qf[2];
    #pragma unroll
    for (int c = 0; c < 2; ++c) {
        const float* src = base + (size_t)(t0 + wv * 16 + col) * 768 + h * 64 + c * 32 + hi * 8;
        float4 u0 = *(const float4*)src, u1 = *(const float4*)(src + 4);
        u0.x *= 0.125f; u0.y *= 0.125f; u0.z *= 0.125f; u0.w *= 0.125f;
        u1.x *= 0.125f; u1.y *= 0.125f; u1.z *= 0.125f; u1.w *= 0.125f;
        qf[c] = pack8(u0, u1);
    }
    f32x4 oacc[4] = {};
    float mrow[4] = {-3.4e38f, -3.4e38f, -3.4e38f, -3.4e38f};
    float lrow[4] = {};
    const int srow = tid >> 2, sdblk = (tid & 3) * 16;
    const int vs = tid & 63, vdblk = (tid >> 6) * 16;

    for (int st = 0; st < 16; ++st) {
        {
            const float* kp = base + (size_t)(st * 64 + srow) * 768 + 256 + h * 64 + sdblk;
            float4 k0 = *(const float4*)kp, k1 = *(const float4*)(kp + 4);
            float4 k2 = *(const float4*)(kp + 8), k3 = *(const float4*)(kp + 12);
            *(f16x8*)&ks[srow][sdblk] = pack8(k0, k1);
            *(f16x8*)&ks[srow][sdblk + 8] = pack8(k2, k3);
            const float* vp = base + (size_t)(st * 64 + vs) * 768 + 512 + h * 64 + vdblk;
            float4 v0 = *(const float4*)vp, v1 = *(const float4*)(vp + 4);
            float4 v2 = *(const float4*)(vp + 8), v3 = *(const float4*)(vp + 12);
            float vv[16] = {v0.x, v0.y, v0.z, v0.w, v1.x, v1.y, v1.z, v1.w,
                            v2.x, v2.y, v2.z, v2.w, v3.x, v3.y, v3.z, v3.w};
            #pragma unroll
            for (int i = 0; i < 16; ++i) vts[vdblk + i][vs] = (_Float16)vv[i];
        }
        __syncthreads();
        f32x4 sacc[4] = {};
        #pragma unroll
        for (int c = 0; c < 2; ++c) {
            #pragma unroll
            for (int j = 0; j < 4; ++j) {
                f16x8 bfr = *(const f16x8*)&ks[j * 16 + col][c * 32 + hi * 8];
                sacc[j] = __builtin_amdgcn_mfma_f32_16x16x32_f16(qf[c], bfr, sacc[j], 0, 0, 0);
            }
        }
        #pragma unroll
        for (int r = 0; r < 4; ++r) {
            float tm = fmaxf(fmaxf(sacc[0][r], sacc[1][r]), fmaxf(sacc[2][r], sacc[3][r]));
            tm = fmaxf(tm, __shfl_xor(tm, 1));
            tm = fmaxf(tm, __shfl_xor(tm, 2));
            tm = fmaxf(tm, __shfl_xor(tm, 4));
            tm = fmaxf(tm, __shfl_xor(tm, 8));
            const float mn = fmaxf(mrow[r], tm);
            const float corr = __expf(mrow[r] - mn);
            mrow[r] = mn;
            float lsum = 0.f;
            #pragma unroll
            for (int j = 0; j < 4; ++j) {
                float pv = __expf(sacc[j][r] - mn);
                _Float16 p16 = (_Float16)pv;
                ps[wv * 16 + hi * 4 + r][j * 16 + col] = p16;
                lsum += (float)p16;
            }
            lsum += __shfl_xor(lsum, 1);
            lsum += __shfl_xor(lsum, 2);
            lsum += __shfl_xor(lsum, 4);
            lsum += __shfl_xor(lsum, 8);
            lrow[r] = lrow[r] * corr + lsum;
            #pragma unroll
            for (int j = 0; j < 4; ++j) oacc[j][r] *= corr;
        }
        #pragma unroll
        for (int c = 0; c < 2; ++c) {
            f16x8 a = *(const f16x8*)&ps[wv * 16 + col][c * 32 + hi * 8];
            #pragma unroll
            for (int j = 0; j < 4; ++j) {
                f16x8 bfr = *(const f16x8*)&vts[j * 16 + col][c * 32 + hi * 8];
                oacc[j] = __builtin_amdgcn_mfma_f32_16x16x32_f16(a, bfr, oacc[j], 0, 0, 0);
            }
        }
        __syncthreads();
    }
    float inv[4];
    #pragma unroll
    for (int r = 0; r < 4; ++r) inv[r] = 1.f / lrow[r];
    #pragma unroll
    for (int j = 0; j < 4; ++j)
        #pragma unroll
        for (int r = 0; r < 4; ++r)
            o[((size_t)(b * 1024 + t0 + wv * 16 + hi * 4 + r)) * 256 + h * 64 + j * 16 + col]
                = oacc[j][r] * inv[r];
}

// ---------------- mean over T ----------------
__global__ __launch_bounds__(256) void pool_mean(const float* __restrict__ o, float* __restrict__ opool)
{
    const int b = blockIdx.x >> 3, chunk = blockIdx.x & 7;
    const int d = threadIdx.x;
    float s = 0.f;
    for (int t = chunk * 128; t < chunk * 128 + 128; ++t)
        s += o[((size_t)(b * 1024 + t)) * 256 + d];
    atomicAdd(&opool[b * 256 + d], s * (1.f / 1024.f));
}

// ---------------- head ----------------
__global__ __launch_bounds__(256) void head_k(
    const float* __restrict__ opool, const float* __restrict__ wout, const float* __restrict__ bout,
    const float* __restrict__ f1w, const float* __restrict__ f1b,
    const float* __restrict__ f2w, const float* __restrict__ f2b,
    float* __restrict__ outp)
{
    __shared__ float op[256], pooled[256], hid[128];
    const int b = blockIdx.x, e = threadIdx.x;
    op[e] = opool[b * 256 + e];
    __syncthreads();
    float s = bout[e];
    for (int d = 0; d < 256; d += 4) {
        float4 w4 = *(const float4*)(wout + (size_t)e * 256 + d);
        s += op[d] * w4.x + op[d + 1] * w4.y + op[d + 2] * w4.z + op[d + 3] * w4.w;
    }
    pooled[e] = s;
    __syncthreads();
    if (e < 128) {
        float s2 = f1b[e];
        for (int d = 0; d < 256; d += 4) {
            float4 w4 = *(const float4*)(f1w + (size_t)e * 256 + d);
            s2 += pooled[d] * w4.x + pooled[d + 1] * w4.y + pooled[d + 2] * w4.z + pooled[d + 3] * w4.w;
        }
        hid[e] = fmaxf(s2, 0.f);
    }
    __syncthreads();
    if (e < 2) {
        float s3 = f2b[e];
        for (int j = 0; j < 128; ++j) s3 += hid[j] * f2w[e * 128 + j];
        outp[b * 2 + e] = s3;
    }
}

extern "C" void kernel_launch(void* const* d_in, const int* in_sizes, int n_in,
                              void* d_out, int out_size, void* d_ws, size_t ws_size,
                              hipStream_t stream)
{
    const float* x         = (const float*)d_in[0];
    const float* w_ih0     = (const float*)d_in[1];
    const float* w_hh0     = (const float*)d_in[2];
    const float* b_ih0     = (const float*)d_in[3];
    const float* b_hh0     = (const float*)d_in[4];
    const float* w_ih1     = (const float*)d_in[5];
    const float* w_hh1     = (const float*)d_in[6];
    const float* b_ih1     = (const float*)d_in[7];
    const float* b_hh1     = (const float*)d_in[8];
    const float* gat_W     = (const float*)d_in[9];
    const float* gat_a     = (const float*)d_in[10];
    const float* ln_g      = (const float*)d_in[11];
    const float* ln_b      = (const float*)d_in[12];
    const float* mha_in_w  = (const float*)d_in[13];
    const float* mha_in_b  = (const float*)d_in[14];
    const float* mha_out_w = (const float*)d_in[15];
    const float* mha_out_b = (const float*)d_in[16];
    const float* fc1_w     = (const float*)d_in[17];
    const float* fc1_b     = (const float*)d_in[18];
    const float* fc2_w     = (const float*)d_in[19];
    const float* fc2_b     = (const float*)d_in[20];
    float* out = (float*)d_out;

    float* xpbuf = (float*)d_ws;                       // [B*T][768] xp0 -> xp1 (in place)
    float* buf1  = xpbuf + (size_t)B_ * T_ * G3_;      // [B*T][256] (h1-f16 during scans; gat/h after)
    float* buf2  = buf1 + (size_t)B_ * T_ * H_;        // [B*T][256] (gru_out)
    float* buf3  = buf2 + (size_t)B_ * T_ * H_;        // [B*T][256] (hk / o)
    float* W2    = buf3 + (size_t)B_ * T_ * H_;        // 65536
    float* e1    = W2 + 65536;
    float* e2    = e1 + 65536;
    float* opool = e2 + 65536;                         // 4096 floats
    int*   flags = (int*)(opool + 4096);               // 512 ints (flagA + flagB)
    _Float16* wih1h = (_Float16*)(flags + 512);        // 196608 f16
    _Float16* h1buf = (_Float16*)buf1;                 // overlay: h1 (f16) during scans

    dim3 blk(256);
    gatw_t<<<dim3(256), blk, 0, stream>>>(gat_W, W2);
    prep_wih1<<<dim3(192), blk, 0, stream>>>(w_ih1, wih1h);
    // xp0 = x @ w_ih0^T + b_ih0   (M=B*T, N=G3, K=IN)
    gemm16<<<dim3(G3_ / 64, (B_ * T_) / 64), blk, 0, stream>>>(x, w_ih0, b_ih0, xpbuf, B_ * T_, G3_, IN_);
    // zero opool + flags (single contiguous region)
    hipMemsetAsync(opool, 0, 4096 * sizeof(float) + 512 * sizeof(int), stream);
    // 3-stage pipelined scans: L0 (0-15) -> G (16-31) -> L1 (32-47)
    fused_gru<<<dim3(48), dim3(512), 0, stream>>>(xpbuf, w_hh0, b_hh0, w_hh1, b_hh1,
                                                  wih1h, b_ih1, h1buf, buf2, flags);
    // hk = gru_out @ W2^T -> buf3   (M=B*T, N=H, K=H)
    gemm16<<<dim3(H_ / 64, (B_ * T_) / 64), blk, 0, stream>>>(buf2, W2, nullptr, buf3, B_ * T_, H_, H_);
    gat_e<<<dim3(8, 4, 16), blk, 0, stream>>>(buf3, gat_a, e1, e2);
    gat_attn<<<dim3(16, 4, 16), blk, 0, stream>>>(buf3, e1, e2, buf1);
    add_ln<<<dim3(B_ * T_), dim3(64), 0, stream>>>(buf2, buf1, ln_g, ln_b, buf1);
    // qkv = h @ mha_in_w^T + b -> xpbuf   (M=B*T, N=G3, K=H)
    gemm16<<<dim3(G3_ / 64, (B_ * T_) / 64), blk, 0, stream>>>(buf1, mha_in_w, mha_in_b, xpbuf, B_ * T_, G3_, H_);
    mha_attn<<<dim3(16, 4, 16), blk, 0, stream>>>(xpbuf, buf3);
    pool_mean<<<dim3(128), blk, 0, stream>>>(buf3, opool);
    head_k<<<dim3(16), blk, 0, stream>>>(opool, mha_out_w, mha_out_b, fc1_w, fc1_b, fc2_w, fc2_b, out);
}

// Round 15
// 1563.537 us; speedup vs baseline: 1.8595x; 1.0089x over previous
//
#include <hip/hip_runtime.h>
#include <hip/hip_bf16.h>

// GNNClassifier: 2x GRU(scan, 3-stage pipelined) -> GAT -> LN -> MHA -> pool -> FC
// B=16 T=1024 IN=64 H=256 G3=768 K=4 F=64 NH=4 HD=64 C=2
// Round-15: round-14's verified 3-stage fused_gru (L0 scan -> G gemm -> L1 scan)
// with 1024-THREAD scan blocks: 16 waves, ONE unit per thread -> 24 f16x8 weight
// fragments = 96 VGPR, fits the 128-VGPR/4-wave-per-SIMD budget so recurrent
// weights stay register-resident (the ~600cy/step L2 re-fetch gap measured since
// round 3). Per-SIMD MFMA load unchanged (4 waves x 24 = 96/step). This is
// round 9's restructure, whose failure is now proven to have been the launcher
// bug (rounds 11/12). G role redistributed over 16 waves (mt=wv&3, jgrp=wv>>2).

#define B_ 16
#define T_ 1024
#define IN_ 64
#define H_ 256
#define G3_ 768
#define CHUNK 64
#define NCH (T_ / CHUNK)

typedef _Float16 f16x8 __attribute__((ext_vector_type(8)));
typedef float f32x4 __attribute__((ext_vector_type(4)));

__device__ __forceinline__ float fastrcp(float x) { return __builtin_amdgcn_rcpf(x); }
__device__ __forceinline__ float sigmoidf_(float x) { return fastrcp(1.f + __expf(-x)); }
__device__ __forceinline__ float tanh_fast(float x) {
    float t = __expf(-2.f * fabsf(x));
    float r = (1.f - t) * fastrcp(1.f + t);
    return x >= 0.f ? r : -r;
}

__device__ __forceinline__ f16x8 pack8(float4 a, float4 b) {
    f16x8 v;
    v[0] = (_Float16)a.x; v[1] = (_Float16)a.y; v[2] = (_Float16)a.z; v[3] = (_Float16)a.w;
    v[4] = (_Float16)b.x; v[5] = (_Float16)b.y; v[6] = (_Float16)b.z; v[7] = (_Float16)b.w;
    return v;
}

// ---------------- f16-MFMA tiled GEMM: Y[M][N] = X[M][Kd] @ W[N][Kd]^T + bias ----------------
__global__ __launch_bounds__(256) void gemm16(
    const float* __restrict__ X, const float* __restrict__ W,
    const float* __restrict__ bias, float* __restrict__ Y,
    int M, int N, int Kd)
{
    __shared__ _Float16 As[2][64][40];
    __shared__ _Float16 Bs[2][64][40];
    const int tid = threadIdx.x;
    const int wv = tid >> 6, lane = tid & 63;
    const int col = lane & 15, hi = lane >> 4;
    const int bm = blockIdx.y * 64, bn = blockIdx.x * 64;
    const int srow = tid >> 2, scol = (tid & 3) * 8;
    const float* xrow = X + (size_t)(bm + srow) * Kd + scol;
    const float* wrow = W + (size_t)(bn + srow) * Kd + scol;
    const int nk = Kd >> 5;

    {
        float4 a0 = *(const float4*)(xrow);
        float4 a1 = *(const float4*)(xrow + 4);
        float4 b0 = *(const float4*)(wrow);
        float4 b1 = *(const float4*)(wrow + 4);
        *(f16x8*)&As[0][srow][scol] = pack8(a0, a1);
        *(f16x8*)&Bs[0][srow][scol] = pack8(b0, b1);
    }
    __syncthreads();
    f32x4 acc[4] = {};
    for (int kc = 0; kc < nk; ++kc) {
        const int cur = kc & 1;
        f16x8 va, vb;
        const bool have = (kc + 1 < nk);
        if (have) {
            const float* xa = xrow + (kc + 1) * 32;
            const float* wa = wrow + (kc + 1) * 32;
            float4 a0 = *(const float4*)xa, a1 = *(const float4*)(xa + 4);
            float4 b0 = *(const float4*)wa, b1 = *(const float4*)(wa + 4);
            va = pack8(a0, a1);
            vb = pack8(b0, b1);
        }
        f16x8 a = *(const f16x8*)&As[cur][wv * 16 + col][hi * 8];
        #pragma unroll
        for (int j = 0; j < 4; ++j) {
            f16x8 bfr = *(const f16x8*)&Bs[cur][j * 16 + col][hi * 8];
            acc[j] = __builtin_amdgcn_mfma_f32_16x16x32_f16(a, bfr, acc[j], 0, 0, 0);
        }
        if (have) {
            *(f16x8*)&As[cur ^ 1][srow][scol] = va;
            *(f16x8*)&Bs[cur ^ 1][srow][scol] = vb;
        }
        __syncthreads();
    }
    #pragma unroll
    for (int j = 0; j < 4; ++j) {
        const int n = bn + j * 16 + col;
        const float bv = bias ? bias[n] : 0.f;
        #pragma unroll
        for (int r = 0; r < 4; ++r) {
            const int m = bm + wv * 16 + hi * 4 + r;
            Y[(size_t)m * N + n] = acc[j][r] + bv;
        }
    }
}

// ---------------- fused 3-stage pipelined GRU (1024-thread blocks) ----------------
// 48 blocks: role = blockIdx.x>>4 (0=L0 scan, 1=G xp1-gemm, 2=L1 scan), b = blockIdx.x&15.
// Scan (L0/L1): 16 waves; wave wv owns units [wv*16, wv*16+16); each thread holds
// ONE unit's 3 gate weight rows as 24 f16x8 (96 VGPR, register-resident).
// L0 streams h1 (f16, coalesced) to h1b; releases flagA[b][c] per chunk.
// G: 16 waves (mt=wv&3 m-tile, jgrp=wv>>2 -> 12 n-tiles); waits flagA; writes xp1
//    IN PLACE over consumed xp0; releases flagB[b][c].
// L1: waits flagB; scans layer 1; writes gru_out.
// Flag/fence pattern byte-identical to the verified round-14 kernel.
__global__ __launch_bounds__(1024, 1) void fused_gru(
    float* xp,                        // [B][T][768] xp0 in, overwritten by xp1 per chunk
    const float* __restrict__ w_hh0, const float* __restrict__ b_hh0,
    const float* __restrict__ w_hh1, const float* __restrict__ b_hh1,
    const _Float16* __restrict__ w_ih1h, const float* __restrict__ b_ih1,
    _Float16* h1b,                    // [B][T][256] f16 (layer-0 output stream)
    float* __restrict__ ys,           // [B][T][256] gru_out
    int* flags)                       // [0..255]=flagA[b][c], [256..511]=flagB[b][c]
{
    __shared__ _Float16 hbuf[2][272];
    const int tid = threadIdx.x;
    const int lane = tid & 63;
    const int wv = tid >> 6;          // wave 0..15
    const int col = lane & 15;
    const int hi = lane >> 4;
    const int role = blockIdx.x >> 4;
    const int b = blockIdx.x & 15;

    if (role == 1) {
        // ---- G: xp1 chunk GEMM (M=64 x N=768), 16 waves: mt=wv&3, jgrp=wv>>2 (12 n-tiles)
        const int mt = wv & 3;
        const int jbase = (wv >> 2) * 12;
        float* xbase = xp + (size_t)b * T_ * G3_;
        const _Float16* hbase = h1b + (size_t)b * T_ * H_;
        for (int c = 0; c < NCH; ++c) {
            const int t0 = c * CHUNK;
            if (tid == 0) {
                while (__hip_atomic_load(&flags[b * NCH + c], __ATOMIC_ACQUIRE,
                                         __HIP_MEMORY_SCOPE_AGENT) == 0)
                    __builtin_amdgcn_s_sleep(8);
                __threadfence();
            }
            __syncthreads();
            f16x8 af[8];
            #pragma unroll
            for (int kk = 0; kk < 8; ++kk)
                af[kk] = *(const f16x8*)(hbase + (size_t)(t0 + mt * 16 + col) * H_ + kk * 32 + hi * 8);
            for (int j = 0; j < 12; ++j) {
                const int n = (jbase + j) * 16 + col;
                f16x8 bfr[8];
                #pragma unroll
                for (int kk = 0; kk < 8; ++kk)
                    bfr[kk] = *(const f16x8*)(w_ih1h + (size_t)n * 256 + kk * 32 + hi * 8);
                f32x4 ga = {};
                #pragma unroll
                for (int kk = 0; kk < 8; ++kk)
                    ga = __builtin_amdgcn_mfma_f32_16x16x32_f16(af[kk], bfr[kk], ga, 0, 0, 0);
                const float bv = b_ih1[n];
                #pragma unroll
                for (int r = 0; r < 4; ++r)
                    xbase[(size_t)(t0 + mt * 16 + hi * 4 + r) * G3_ + n] = ga[r] + bv;
            }
            asm volatile("s_waitcnt vmcnt(0)" ::: "memory");
            __syncthreads();
            if (tid == 0) {
                __threadfence();
                __hip_atomic_store(&flags[256 + b * NCH + c], 1, __ATOMIC_RELEASE,
                                   __HIP_MEMORY_SCOPE_AGENT);
            }
        }
        return;
    }

    // ---- scan path (L0 or L1), 16 waves, 1 unit/thread ----
    const bool isL0 = (role == 0);
    const float* wm = isL0 ? w_hh0 : w_hh1;
    const float* bbp = isL0 ? b_hh0 : b_hh1;

    const int unit = wv * 16 + col;
    f16x8 bf[3][8];                   // 24 f16x8 = 96 VGPR: register-resident
    float bias_[3];
    #pragma unroll
    for (int g = 0; g < 3; ++g) {
        const int n = g * 256 + unit;
        bias_[g] = bbp[n];
        #pragma unroll
        for (int c = 0; c < 8; ++c) {
            const float* src = wm + (size_t)n * 256 + c * 32 + hi * 8;
            float4 u0 = *(const float4*)(src);
            float4 u1 = *(const float4*)(src + 4);
            bf[g][c] = pack8(u0, u1);
        }
    }
    float hold = 0.f;
    if (tid < 256) hbuf[0][tid] = (_Float16)0.f;
    __syncthreads();

    float* xbase = xp + (size_t)b * T_ * G3_;
    float* ybase = ys + (size_t)b * T_ * H_;
    _Float16* hbase = h1b + (size_t)b * T_ * H_;

    float pref[3];
    if (isL0) {
        #pragma unroll
        for (int g = 0; g < 3; ++g)
            pref[g] = xbase[g * 256 + unit];
    }

    int cur = 0;
    for (int c = 0; c < NCH; ++c) {
        const int t0 = c * CHUNK;
        if (!isL0) {
            if (tid == 0) {
                while (__hip_atomic_load(&flags[256 + b * NCH + c], __ATOMIC_ACQUIRE,
                                         __HIP_MEMORY_SCOPE_AGENT) == 0)
                    __builtin_amdgcn_s_sleep(8);
                __threadfence();
            }
            __syncthreads();
            #pragma unroll
            for (int g = 0; g < 3; ++g)
                pref[g] = xbase[(size_t)t0 * G3_ + g * 256 + unit];
        }
        for (int tt = 0; tt < CHUNK; ++tt) {
            const int t = t0 + tt;
            float xv[3];
            #pragma unroll
            for (int g = 0; g < 3; ++g) xv[g] = pref[g];
            // prefetch next step (L0: global next; L1: clamp inside ready chunk)
            const int tn = isL0 ? ((t < T_ - 1) ? t + 1 : t)
                                : ((tt < CHUNK - 1) ? t + 1 : t);
            #pragma unroll
            for (int g = 0; g < 3; ++g)
                pref[g] = xbase[(size_t)tn * G3_ + g * 256 + unit];

            f32x4 acc[3] = {};
            #pragma unroll
            for (int cc = 0; cc < 8; ++cc) {
                f16x8 a = *(const f16x8*)(&hbuf[cur][cc * 32 + hi * 8]); // broadcast A
                #pragma unroll
                for (int g = 0; g < 3; ++g)
                    acc[g] = __builtin_amdgcn_mfma_f32_16x16x32_f16(a, bf[g][cc], acc[g], 0, 0, 0);
            }

            const int nxt = cur ^ 1;
            {
                float ghr = acc[0][0] + bias_[0];
                float ghz = acc[1][0] + bias_[1];
                float ghn = acc[2][0] + bias_[2];
                float r = sigmoidf_(xv[0] + ghr);
                float z = sigmoidf_(xv[1] + ghz);
                float nn = tanh_fast(xv[2] + r * ghn);
                float hv = (1.f - z) * nn + z * hold;
                hold = hv;
                if (hi == 0) {
                    _Float16 h16 = (_Float16)hv;
                    hbuf[nxt][unit] = h16;
                    if (isL0) hbase[(size_t)t * H_ + unit] = h16;   // coalesced f16 stream
                    else      ybase[(size_t)t * H_ + unit] = hv;
                }
            }
            // raw barrier: drain LDS only; keep xp prefetch + stores in flight
            asm volatile("s_waitcnt lgkmcnt(0)" ::: "memory");
            __builtin_amdgcn_s_barrier();
            asm volatile("" ::: "memory");
            cur = nxt;
        }
        if (isL0) {
            asm volatile("s_waitcnt vmcnt(0)" ::: "memory");
            __syncthreads();
            if (tid == 0) {
                __threadfence();
                __hip_atomic_store(&flags[b * NCH + c], 1, __ATOMIC_RELEASE,
                                   __HIP_MEMORY_SCOPE_AGENT);
            }
        }
    }
}

// ---------------- prep: gat_W transpose + w_ih1 -> f16 ----------------
__global__ void gatw_t(const float* __restrict__ gw, float* __restrict__ W2)
{
    int idx = blockIdx.x * 256 + threadIdx.x;
    int n = idx >> 8, d = idx & 255;
    W2[idx] = gw[(size_t)(n >> 6) * 16384 + (size_t)d * 64 + (n & 63)];
}

__global__ void prep_wih1(const float* __restrict__ w, _Float16* __restrict__ wh)
{
    int i = (blockIdx.x * 256 + threadIdx.x) * 4; // 196608 elems
    float4 v = *(const float4*)(w + i);
    wh[i + 0] = (_Float16)v.x; wh[i + 1] = (_Float16)v.y;
    wh[i + 2] = (_Float16)v.z; wh[i + 3] = (_Float16)v.w;
}

// ---------------- e1/e2 ----------------
__global__ __launch_bounds__(256) void gat_e(
    const float* __restrict__ hk, const float* __restrict__ ga,
    float* __restrict__ e1, float* __restrict__ e2)
{
    __shared__ float tile[128][65];
    __shared__ float a1s[64], a2s[64];
    const int tt = blockIdx.x, k = blockIdx.y, b = blockIdx.z;
    const int tid = threadIdx.x;
    if (tid < 64) { a1s[tid] = ga[k * 128 + tid]; a2s[tid] = ga[k * 128 + 64 + tid]; }
    #pragma unroll
    for (int rep = 0; rep < 32; ++rep) {
        int idx = rep * 256 + tid; int tl = idx >> 6, f = idx & 63;
        tile[tl][f] = hk[((size_t)(b * 1024 + tt * 128 + tl)) * 256 + k * 64 + f];
    }
    __syncthreads();
    if (tid < 128) {
        float s1 = 0.f, s2 = 0.f;
        #pragma unroll 8
        for (int f = 0; f < 64; ++f) {
            float hv = tile[tid][f];
            s1 += hv * a1s[f]; s2 += hv * a2s[f];
        }
        const size_t o = (size_t)(b * 4 + k) * 1024 + tt * 128 + tid;
        e1[o] = s1; e2[o] = s2;
    }
}

// ---------------- GAT attention (MFMA PV, monotone-leaky exact max) ----------------
__global__ __launch_bounds__(256) void gat_attn(
    const float* __restrict__ hk, const float* __restrict__ e1,
    const float* __restrict__ e2, float* __restrict__ outp)
{
    __shared__ _Float16 hkT[64][72];
    __shared__ float e1s[64], e2s[64], lssh[64];
    __shared__ float red[4];
    const int tid = threadIdx.x;
    const int wv = tid >> 6, lane = tid & 63;
    const int col = lane & 15, hi = lane >> 4;
    const int tt = blockIdx.x, k = blockIdx.y, b = blockIdx.z;
    const int t0 = tt * 64;
    const float* e2row = e2 + (size_t)(b * 4 + k) * 1024;
    if (tid < 64) e1s[tid] = e1[(size_t)(b * 4 + k) * 1024 + t0 + tid];
    float m = -3.4e38f;
    for (int i = tid; i < 1024; i += 256) m = fmaxf(m, e2row[i]);
    #pragma unroll
    for (int off = 1; off < 64; off <<= 1) m = fmaxf(m, __shfl_xor(m, off));
    if (lane == 0) red[wv] = m;
    __syncthreads();
    const float e2max = fmaxf(fmaxf(red[0], red[1]), fmaxf(red[2], red[3]));
    const float e1A = e1s[wv * 16 + col];
    const float eAm = e1A + e2max;
    const float mA = (eAm > 0.f) ? eAm : 0.2f * eAm;

    float lsum = 0.f;
    f32x4 oacc[4] = {};
    const int vs = tid & 63, vfblk = (tid >> 6) * 16;
    for (int st = 0; st < 16; ++st) {
        {
            const float* hp = hk + ((size_t)(b * 1024 + st * 64 + vs)) * 256 + k * 64 + vfblk;
            float4 v0 = *(const float4*)hp, v1 = *(const float4*)(hp + 4);
            float4 v2 = *(const float4*)(hp + 8), v3 = *(const float4*)(hp + 12);
            float vv[16] = {v0.x, v0.y, v0.z, v0.w, v1.x, v1.y, v1.z, v1.w,
                            v2.x, v2.y, v2.z, v2.w, v3.x, v3.y, v3.z, v3.w};
            #pragma unroll
            for (int i = 0; i < 16; ++i) hkT[vfblk + i][vs] = (_Float16)vv[i];
        }
        if (tid < 64) e2s[tid] = e2row[st * 64 + tid];
        __syncthreads();
        #pragma unroll
        for (int c = 0; c < 2; ++c) {
            f16x8 af;
            #pragma unroll
            for (int i = 0; i < 8; ++i) {
                float e = e1A + e2s[c * 32 + hi * 8 + i];
                e = (e > 0.f) ? e : 0.2f * e;
                float pv = __expf(e - mA);
                _Float16 p16 = (_Float16)pv;
                af[i] = p16;
                lsum += (float)p16;
            }
            #pragma unroll
            for (int j = 0; j < 4; ++j) {
                f16x8 bfr = *(const f16x8*)&hkT[j * 16 + col][c * 32 + hi * 8];
                oacc[j] = __builtin_amdgcn_mfma_f32_16x16x32_f16(af, bfr, oacc[j], 0, 0, 0);
            }
        }
        __syncthreads();
    }
    lsum += __shfl_xor(lsum, 16);
    lsum += __shfl_xor(lsum, 32);
    if (hi == 0) lssh[wv * 16 + col] = lsum;
    #pragma unroll
    for (int r = 0; r < 4; ++r) {
        const float inv = 1.f / lssh[wv * 16 + hi * 4 + r];
        #pragma unroll
        for (int j = 0; j < 4; ++j)
            outp[((size_t)(b * 1024 + t0 + wv * 16 + hi * 4 + r)) * 256 + k * 64 + j * 16 + col]
                = oacc[j][r] * inv;
    }
}

// ---------------- residual + LayerNorm ----------------
__global__ __launch_bounds__(64) void add_ln(
    const float* __restrict__ a, const float* bb,
    const float* __restrict__ gamma, const float* __restrict__ beta,
    float* outp)
{
    const int row = blockIdx.x;
    const int lane = threadIdx.x;
    const size_t base = (size_t)row * 256 + lane * 4;
    float4 va = *(const float4*)(a + base);
    float4 vb = *(const float4*)(bb + base);
    float xv[4] = {va.x + vb.x, va.y + vb.y, va.z + vb.z, va.w + vb.w};
    float s = xv[0] + xv[1] + xv[2] + xv[3];
    float s2 = xv[0] * xv[0] + xv[1] * xv[1] + xv[2] * xv[2] + xv[3] * xv[3];
    #pragma unroll
    for (int off = 32; off >= 1; off >>= 1) {
        s += __shfl_xor(s, off);
        s2 += __shfl_xor(s2, off);
    }
    const float mu = s * (1.f / 256.f);
    const float var = s2 * (1.f / 256.f) - mu * mu;
    const float rs = rsqrtf(var + 1e-5f);
    float4 g4 = *(const float4*)(gamma + lane * 4);
    float4 b4 = *(const float4*)(beta + lane * 4);
    float4 ov;
    ov.x = (xv[0] - mu) * rs * g4.x + b4.x;
    ov.y = (xv[1] - mu) * rs * g4.y + b4.y;
    ov.z = (xv[2] - mu) * rs * g4.z + b4.z;
    ov.w = (xv[3] - mu) * rs * g4.w + b4.w;
    *(float4*)(outp + base) = ov;
}

// ---------------- MHA flash attention (MFMA QK^T + PV) ----------------
__global__ __launch_bounds__(256) void mha_attn(const float* __restrict__ qkv, float* __restrict__ o)
{
    __shared__ _Float16 ks[64][72];
    __shared__ _Float16 vts[64][72];
    __shared__ _Float16 ps[64][72];
    const int tid = threadIdx.x;
    const int wv = tid >> 6, lane = tid & 63;
    const int col = lane & 15, hi = lane >> 4;
    const int tt = blockIdx.x, h = blockIdx.y, b = blockIdx.z;
    const int t0 = tt * 64;
    const float* base = qkv + (size_t)b * 1024 * 768;

    f16x8 qf[2];
    #pragma unroll
    for (int c = 0; c < 2; ++c) {
        const float* src = base + (size_t)(t0 + wv * 16 + col) * 768 + h * 64 + c * 32 + hi * 8;
        float4 u0 = *(const float4*)src, u1 = *(const float4*)(src + 4);
        u0.x *= 0.125f; u0.y *= 0.125f; u0.z *= 0.125f; u0.w *= 0.125f;
        u1.x *= 0.125f; u1.y *= 0.125f; u1.z *= 0.125f; u1.w *= 0.125f;
        qf[c] = pack8(u0, u1);
    }
    f32x4 oacc[4] = {};
    float mrow[4] = {-3.4e38f, -3.4e38f, -3.4e38f, -3.4e38f};
    float lrow[4] = {};
    const int srow = tid >> 2, sdblk = (tid & 3) * 16;
    const int vs = tid & 63, vdblk = (tid >> 6) * 16;

    for (int st = 0; st < 16; ++st) {
        {
            const float* kp = base + (size_t)(st * 64 + srow) * 768 + 256 + h * 64 + sdblk;
            float4 k0 = *(const float4*)kp, k1 = *(const float4*)(kp + 4);
            float4 k2 = *(const float4*)(kp + 8), k3 = *(const float4*)(kp + 12);
            *(f16x8*)&ks[srow][sdblk] = pack8(k0, k1);
            *(f16x8*)&ks[srow][sdblk + 8] = pack8(k2, k3);
            const float* vp = base + (size_t)(st * 64 + vs) * 768 + 512 + h * 64 + vdblk;
            float4 v0 = *(const float4*)vp, v1 = *(const float4*)(vp + 4);
            float4 v2 = *(const float4*)(vp + 8), v3 = *(const float4*)(vp + 12);
            float vv[16] = {v0.x, v0.y, v0.z, v0.w, v1.x, v1.y, v1.z, v1.w,
                            v2.x, v2.y, v2.z, v2.w, v3.x, v3.y, v3.z, v3.w};
            #pragma unroll
            for (int i = 0; i < 16; ++i) vts[vdblk + i][vs] = (_Float16)vv[i];
        }
        __syncthreads();
        f32x4 sacc[4] = {};
        #pragma unroll
        for (int c = 0; c < 2; ++c) {
            #pragma unroll
            for (int j = 0; j < 4; ++j) {
                f16x8 bfr = *(const f16x8*)&ks[j * 16 + col][c * 32 + hi * 8];
                sacc[j] = __builtin_amdgcn_mfma_f32_16x16x32_f16(qf[c], bfr, sacc[j], 0, 0, 0);
            }
        }
        #pragma unroll
        for (int r = 0; r < 4; ++r) {
            float tm = fmaxf(fmaxf(sacc[0][r], sacc[1][r]), fmaxf(sacc[2][r], sacc[3][r]));
            tm = fmaxf(tm, __shfl_xor(tm, 1));
            tm = fmaxf(tm, __shfl_xor(tm, 2));
            tm = fmaxf(tm, __shfl_xor(tm, 4));
            tm = fmaxf(tm, __shfl_xor(tm, 8));
            const float mn = fmaxf(mrow[r], tm);
            const float corr = __expf(mrow[r] - mn);
            mrow[r] = mn;
            float lsum = 0.f;
            #pragma unroll
            for (int j = 0; j < 4; ++j) {
                float pv = __expf(sacc[j][r] - mn);
                _Float16 p16 = (_Float16)pv;
                ps[wv * 16 + hi * 4 + r][j * 16 + col] = p16;
                lsum += (float)p16;
            }
            lsum += __shfl_xor(lsum, 1);
            lsum += __shfl_xor(lsum, 2);
            lsum += __shfl_xor(lsum, 4);
            lsum += __shfl_xor(lsum, 8);
            lrow[r] = lrow[r] * corr + lsum;
            #pragma unroll
            for (int j = 0; j < 4; ++j) oacc[j][r] *= corr;
        }
        #pragma unroll
        for (int c = 0; c < 2; ++c) {
            f16x8 a = *(const f16x8*)&ps[wv * 16 + col][c * 32 + hi * 8];
            #pragma unroll
            for (int j = 0; j < 4; ++j) {
                f16x8 bfr = *(const f16x8*)&vts[j * 16 + col][c * 32 + hi * 8];
                oacc[j] = __builtin_amdgcn_mfma_f32_16x16x32_f16(a, bfr, oacc[j], 0, 0, 0);
            }
        }
        __syncthreads();
    }
    float inv[4];
    #pragma unroll
    for (int r = 0; r < 4; ++r) inv[r] = 1.f / lrow[r];
    #pragma unroll
    for (int j = 0; j < 4; ++j)
        #pragma unroll
        for (int r = 0; r < 4; ++r)
            o[((size_t)(b * 1024 + t0 + wv * 16 + hi * 4 + r)) * 256 + h * 64 + j * 16 + col]
                = oacc[j][r] * inv[r];
}

// ---------------- mean over T ----------------
__global__ __launch_bounds__(256) void pool_mean(const float* __restrict__ o, float* __restrict__ opool)
{
    const int b = blockIdx.x >> 3, chunk = blockIdx.x & 7;
    const int d = threadIdx.x;
    float s = 0.f;
    for (int t = chunk * 128; t < chunk * 128 + 128; ++t)
        s += o[((size_t)(b * 1024 + t)) * 256 + d];
    atomicAdd(&opool[b * 256 + d], s * (1.f / 1024.f));
}

// ---------------- head ----------------
__global__ __launch_bounds__(256) void head_k(
    const float* __restrict__ opool, const float* __restrict__ wout, const float* __restrict__ bout,
    const float* __restrict__ f1w, const float* __restrict__ f1b,
    const float* __restrict__ f2w, const float* __restrict__ f2b,
    float* __restrict__ outp)
{
    __shared__ float op[256], pooled[256], hid[128];
    const int b = blockIdx.x, e = threadIdx.x;
    op[e] = opool[b * 256 + e];
    __syncthreads();
    float s = bout[e];
    for (int d = 0; d < 256; d += 4) {
        float4 w4 = *(const float4*)(wout + (size_t)e * 256 + d);
        s += op[d] * w4.x + op[d + 1] * w4.y + op[d + 2] * w4.z + op[d + 3] * w4.w;
    }
    pooled[e] = s;
    __syncthreads();
    if (e < 128) {
        float s2 = f1b[e];
        for (int d = 0; d < 256; d += 4) {
            float4 w4 = *(const float4*)(f1w + (size_t)e * 256 + d);
            s2 += pooled[d] * w4.x + pooled[d + 1] * w4.y + pooled[d + 2] * w4.z + pooled[d + 3] * w4.w;
        }
        hid[e] = fmaxf(s2, 0.f);
    }
    __syncthreads();
    if (e < 2) {
        float s3 = f2b[e];
        for (int j = 0; j < 128; ++j) s3 += hid[j] * f2w[e * 128 + j];
        outp[b * 2 + e] = s3;
    }
}

extern "C" void kernel_launch(void* const* d_in, const int* in_sizes, int n_in,
                              void* d_out, int out_size, void* d_ws, size_t ws_size,
                              hipStream_t stream)
{
    const float* x         = (const float*)d_in[0];
    const float* w_ih0     = (const float*)d_in[1];
    const float* w_hh0     = (const float*)d_in[2];
    const float* b_ih0     = (const float*)d_in[3];
    const float* b_hh0     = (const float*)d_in[4];
    const float* w_ih1     = (const float*)d_in[5];
    const float* w_hh1     = (const float*)d_in[6];
    const float* b_ih1     = (const float*)d_in[7];
    const float* b_hh1     = (const float*)d_in[8];
    const float* gat_W     = (const float*)d_in[9];
    const float* gat_a     = (const float*)d_in[10];
    const float* ln_g      = (const float*)d_in[11];
    const float* ln_b      = (const float*)d_in[12];
    const float* mha_in_w  = (const float*)d_in[13];
    const float* mha_in_b  = (const float*)d_in[14];
    const float* mha_out_w = (const float*)d_in[15];
    const float* mha_out_b = (const float*)d_in[16];
    const float* fc1_w     = (const float*)d_in[17];
    const float* fc1_b     = (const float*)d_in[18];
    const float* fc2_w     = (const float*)d_in[19];
    const float* fc2_b     = (const float*)d_in[20];
    float* out = (float*)d_out;

    float* xpbuf = (float*)d_ws;                       // [B*T][768] xp0 -> xp1 (in place)
    float* buf1  = xpbuf + (size_t)B_ * T_ * G3_;      // [B*T][256] (h1-f16 during scans; gat/h after)
    float* buf2  = buf1 + (size_t)B_ * T_ * H_;        // [B*T][256] (gru_out)
    float* buf3  = buf2 + (size_t)B_ * T_ * H_;        // [B*T][256] (hk / o)
    float* W2    = buf3 + (size_t)B_ * T_ * H_;        // 65536
    float* e1    = W2 + 65536;
    float* e2    = e1 + 65536;
    float* opool = e2 + 65536;                         // 4096 floats
    int*   flags = (int*)(opool + 4096);               // 512 ints (flagA + flagB)
    _Float16* wih1h = (_Float16*)(flags + 512);        // 196608 f16
    _Float16* h1buf = (_Float16*)buf1;                 // overlay: h1 (f16) during scans

    dim3 blk(256);
    gatw_t<<<dim3(256), blk, 0, stream>>>(gat_W, W2);
    prep_wih1<<<dim3(192), blk, 0, stream>>>(w_ih1, wih1h);
    // xp0 = x @ w_ih0^T + b_ih0   (M=B*T, N=G3, K=IN)
    gemm16<<<dim3(G3_ / 64, (B_ * T_) / 64), blk, 0, stream>>>(x, w_ih0, b_ih0, xpbuf, B_ * T_, G3_, IN_);
    // zero opool + flags (single contiguous region)
    hipMemsetAsync(opool, 0, 4096 * sizeof(float) + 512 * sizeof(int), stream);
    // 3-stage pipelined scans: L0 (0-15) -> G (16-31) -> L1 (32-47), 1024 threads
    fused_gru<<<dim3(48), dim3(1024), 0, stream>>>(xpbuf, w_hh0, b_hh0, w_hh1, b_hh1,
                                                   wih1h, b_ih1, h1buf, buf2, flags);
    // hk = gru_out @ W2^T -> buf3   (M=B*T, N=H, K=H)
    gemm16<<<dim3(H_ / 64, (B_ * T_) / 64), blk, 0, stream>>>(buf2, W2, nullptr, buf3, B_ * T_, H_, H_);
    gat_e<<<dim3(8, 4, 16), blk, 0, stream>>>(buf3, gat_a, e1, e2);
    gat_attn<<<dim3(16, 4, 16), blk, 0, stream>>>(buf3, e1, e2, buf1);
    add_ln<<<dim3(B_ * T_), dim3(64), 0, stream>>>(buf2, buf1, ln_g, ln_b, buf1);
    // qkv = h @ mha_in_w^T + b -> xpbuf   (M=B*T, N=G3, K=H)
    gemm16<<<dim3(G3_ / 64, (B_ * T_) / 64), blk, 0, stream>>>(buf1, mha_in_w, mha_in_b, xpbuf, B_ * T_, G3_, H_);
    mha_attn<<<dim3(16, 4, 16), blk, 0, stream>>>(xpbuf, buf3);
    pool_mean<<<dim3(128), blk, 0, stream>>>(buf3, opool);
    head_k<<<dim3(16), blk, 0, stream>>>(opool, mha_out_w, mha_out_b, fc1_w, fc1_b, fc2_w, fc2_b, out);
}

// Round 16
// 1480.388 us; speedup vs baseline: 1.9639x; 1.0562x over previous
//
#include <hip/hip_runtime.h>
#include <hip/hip_bf16.h>

// GNNClassifier: 2x GRU(scan, 3-stage pipelined) -> GAT -> LN -> MHA -> pool -> FC
// B=16 T=1024 IN=64 H=256 G3=768 K=4 F=64 NH=4 HD=64 C=2
// Round-16: round-15's verified kernel with CHUNK 64->32 (halves pipeline fill
// ~90->~45us and L1 end-lag; +16 flag handshakes) and gatw_t moved after
// fused_gru (W2 only feeds the hk GEMM). G role remapped for 32-row chunks:
// mt=wv&1, jbase=(wv>>1)*6. Flag arrays grow to 512 each (flagB at +512);
// memset and wih1h offsets updated accordingly.
// (Round-15 falsified the weight-residency theory: VGPR_Count=64 with same
// scan rate -> in-loop weight reloads were never the bottleneck; remaining gap
// is barrier/handshake stalls in the serial recurrence.)

#define B_ 16
#define T_ 1024
#define IN_ 64
#define H_ 256
#define G3_ 768
#define CHUNK 32
#define NCH (T_ / CHUNK)

typedef _Float16 f16x8 __attribute__((ext_vector_type(8)));
typedef float f32x4 __attribute__((ext_vector_type(4)));

__device__ __forceinline__ float fastrcp(float x) { return __builtin_amdgcn_rcpf(x); }
__device__ __forceinline__ float sigmoidf_(float x) { return fastrcp(1.f + __expf(-x)); }
__device__ __forceinline__ float tanh_fast(float x) {
    float t = __expf(-2.f * fabsf(x));
    float r = (1.f - t) * fastrcp(1.f + t);
    return x >= 0.f ? r : -r;
}

__device__ __forceinline__ f16x8 pack8(float4 a, float4 b) {
    f16x8 v;
    v[0] = (_Float16)a.x; v[1] = (_Float16)a.y; v[2] = (_Float16)a.z; v[3] = (_Float16)a.w;
    v[4] = (_Float16)b.x; v[5] = (_Float16)b.y; v[6] = (_Float16)b.z; v[7] = (_Float16)b.w;
    return v;
}

// ---------------- f16-MFMA tiled GEMM: Y[M][N] = X[M][Kd] @ W[N][Kd]^T + bias ----------------
__global__ __launch_bounds__(256) void gemm16(
    const float* __restrict__ X, const float* __restrict__ W,
    const float* __restrict__ bias, float* __restrict__ Y,
    int M, int N, int Kd)
{
    __shared__ _Float16 As[2][64][40];
    __shared__ _Float16 Bs[2][64][40];
    const int tid = threadIdx.x;
    const int wv = tid >> 6, lane = tid & 63;
    const int col = lane & 15, hi = lane >> 4;
    const int bm = blockIdx.y * 64, bn = blockIdx.x * 64;
    const int srow = tid >> 2, scol = (tid & 3) * 8;
    const float* xrow = X + (size_t)(bm + srow) * Kd + scol;
    const float* wrow = W + (size_t)(bn + srow) * Kd + scol;
    const int nk = Kd >> 5;

    {
        float4 a0 = *(const float4*)(xrow);
        float4 a1 = *(const float4*)(xrow + 4);
        float4 b0 = *(const float4*)(wrow);
        float4 b1 = *(const float4*)(wrow + 4);
        *(f16x8*)&As[0][srow][scol] = pack8(a0, a1);
        *(f16x8*)&Bs[0][srow][scol] = pack8(b0, b1);
    }
    __syncthreads();
    f32x4 acc[4] = {};
    for (int kc = 0; kc < nk; ++kc) {
        const int cur = kc & 1;
        f16x8 va, vb;
        const bool have = (kc + 1 < nk);
        if (have) {
            const float* xa = xrow + (kc + 1) * 32;
            const float* wa = wrow + (kc + 1) * 32;
            float4 a0 = *(const float4*)xa, a1 = *(const float4*)(xa + 4);
            float4 b0 = *(const float4*)wa, b1 = *(const float4*)(wa + 4);
            va = pack8(a0, a1);
            vb = pack8(b0, b1);
        }
        f16x8 a = *(const f16x8*)&As[cur][wv * 16 + col][hi * 8];
        #pragma unroll
        for (int j = 0; j < 4; ++j) {
            f16x8 bfr = *(const f16x8*)&Bs[cur][j * 16 + col][hi * 8];
            acc[j] = __builtin_amdgcn_mfma_f32_16x16x32_f16(a, bfr, acc[j], 0, 0, 0);
        }
        if (have) {
            *(f16x8*)&As[cur ^ 1][srow][scol] = va;
            *(f16x8*)&Bs[cur ^ 1][srow][scol] = vb;
        }
        __syncthreads();
    }
    #pragma unroll
    for (int j = 0; j < 4; ++j) {
        const int n = bn + j * 16 + col;
        const float bv = bias ? bias[n] : 0.f;
        #pragma unroll
        for (int r = 0; r < 4; ++r) {
            const int m = bm + wv * 16 + hi * 4 + r;
            Y[(size_t)m * N + n] = acc[j][r] + bv;
        }
    }
}

// ---------------- fused 3-stage pipelined GRU (1024-thread blocks, CHUNK=32) ----------------
// 48 blocks: role = blockIdx.x>>4 (0=L0 scan, 1=G xp1-gemm, 2=L1 scan), b = blockIdx.x&15.
// Scan (L0/L1): 16 waves; wave wv owns units [wv*16, wv*16+16); 1 unit/thread.
// L0 streams h1 (f16, coalesced) to h1b; releases flagA[b][c] per chunk.
// G: 16 waves (mt=wv&1 m-tile of 16 rows, jbase=(wv>>1)*6 -> 6 n-tiles); waits
//    flagA; writes xp1 IN PLACE over consumed xp0; releases flagB[b][c].
// L1: waits flagB; scans layer 1; writes gru_out.
// Flag/fence pattern identical to the verified round-14/15 kernels.
__global__ __launch_bounds__(1024, 1) void fused_gru(
    float* xp,                        // [B][T][768] xp0 in, overwritten by xp1 per chunk
    const float* __restrict__ w_hh0, const float* __restrict__ b_hh0,
    const float* __restrict__ w_hh1, const float* __restrict__ b_hh1,
    const _Float16* __restrict__ w_ih1h, const float* __restrict__ b_ih1,
    _Float16* h1b,                    // [B][T][256] f16 (layer-0 output stream)
    float* __restrict__ ys,           // [B][T][256] gru_out
    int* flags)                       // [0..511]=flagA[b][c], [512..1023]=flagB[b][c]
{
    __shared__ _Float16 hbuf[2][272];
    const int tid = threadIdx.x;
    const int lane = tid & 63;
    const int wv = tid >> 6;          // wave 0..15
    const int col = lane & 15;
    const int hi = lane >> 4;
    const int role = blockIdx.x >> 4;
    const int b = blockIdx.x & 15;

    if (role == 1) {
        // ---- G: xp1 chunk GEMM (M=32 x N=768), 16 waves: mt=wv&1, jbase=(wv>>1)*6
        const int mt = wv & 1;
        const int jbase = (wv >> 1) * 6;
        float* xbase = xp + (size_t)b * T_ * G3_;
        const _Float16* hbase = h1b + (size_t)b * T_ * H_;
        for (int c = 0; c < NCH; ++c) {
            const int t0 = c * CHUNK;
            if (tid == 0) {
                while (__hip_atomic_load(&flags[b * NCH + c], __ATOMIC_ACQUIRE,
                                         __HIP_MEMORY_SCOPE_AGENT) == 0)
                    __builtin_amdgcn_s_sleep(8);
                __threadfence();
            }
            __syncthreads();
            f16x8 af[8];
            #pragma unroll
            for (int kk = 0; kk < 8; ++kk)
                af[kk] = *(const f16x8*)(hbase + (size_t)(t0 + mt * 16 + col) * H_ + kk * 32 + hi * 8);
            for (int j = 0; j < 6; ++j) {
                const int n = (jbase + j) * 16 + col;
                f16x8 bfr[8];
                #pragma unroll
                for (int kk = 0; kk < 8; ++kk)
                    bfr[kk] = *(const f16x8*)(w_ih1h + (size_t)n * 256 + kk * 32 + hi * 8);
                f32x4 ga = {};
                #pragma unroll
                for (int kk = 0; kk < 8; ++kk)
                    ga = __builtin_amdgcn_mfma_f32_16x16x32_f16(af[kk], bfr[kk], ga, 0, 0, 0);
                const float bv = b_ih1[n];
                #pragma unroll
                for (int r = 0; r < 4; ++r)
                    xbase[(size_t)(t0 + mt * 16 + hi * 4 + r) * G3_ + n] = ga[r] + bv;
            }
            asm volatile("s_waitcnt vmcnt(0)" ::: "memory");
            __syncthreads();
            if (tid == 0) {
                __threadfence();
                __hip_atomic_store(&flags[512 + b * NCH + c], 1, __ATOMIC_RELEASE,
                                   __HIP_MEMORY_SCOPE_AGENT);
            }
        }
        return;
    }

    // ---- scan path (L0 or L1), 16 waves, 1 unit/thread ----
    const bool isL0 = (role == 0);
    const float* wm = isL0 ? w_hh0 : w_hh1;
    const float* bbp = isL0 ? b_hh0 : b_hh1;

    const int unit = wv * 16 + col;
    f16x8 bf[3][8];
    float bias_[3];
    #pragma unroll
    for (int g = 0; g < 3; ++g) {
        const int n = g * 256 + unit;
        bias_[g] = bbp[n];
        #pragma unroll
        for (int c = 0; c < 8; ++c) {
            const float* src = wm + (size_t)n * 256 + c * 32 + hi * 8;
            float4 u0 = *(const float4*)(src);
            float4 u1 = *(const float4*)(src + 4);
            bf[g][c] = pack8(u0, u1);
        }
    }
    float hold = 0.f;
    if (tid < 256) hbuf[0][tid] = (_Float16)0.f;
    __syncthreads();

    float* xbase = xp + (size_t)b * T_ * G3_;
    float* ybase = ys + (size_t)b * T_ * H_;
    _Float16* hbase = h1b + (size_t)b * T_ * H_;

    float pref[3];
    if (isL0) {
        #pragma unroll
        for (int g = 0; g < 3; ++g)
            pref[g] = xbase[g * 256 + unit];
    }

    int cur = 0;
    for (int c = 0; c < NCH; ++c) {
        const int t0 = c * CHUNK;
        if (!isL0) {
            if (tid == 0) {
                while (__hip_atomic_load(&flags[512 + b * NCH + c], __ATOMIC_ACQUIRE,
                                         __HIP_MEMORY_SCOPE_AGENT) == 0)
                    __builtin_amdgcn_s_sleep(8);
                __threadfence();
            }
            __syncthreads();
            #pragma unroll
            for (int g = 0; g < 3; ++g)
                pref[g] = xbase[(size_t)t0 * G3_ + g * 256 + unit];
        }
        for (int tt = 0; tt < CHUNK; ++tt) {
            const int t = t0 + tt;
            float xv[3];
            #pragma unroll
            for (int g = 0; g < 3; ++g) xv[g] = pref[g];
            // prefetch next step (L0: global next; L1: clamp inside ready chunk)
            const int tn = isL0 ? ((t < T_ - 1) ? t + 1 : t)
                                : ((tt < CHUNK - 1) ? t + 1 : t);
            #pragma unroll
            for (int g = 0; g < 3; ++g)
                pref[g] = xbase[(size_t)tn * G3_ + g * 256 + unit];

            f32x4 acc[3] = {};
            #pragma unroll
            for (int cc = 0; cc < 8; ++cc) {
                f16x8 a = *(const f16x8*)(&hbuf[cur][cc * 32 + hi * 8]); // broadcast A
                #pragma unroll
                for (int g = 0; g < 3; ++g)
                    acc[g] = __builtin_amdgcn_mfma_f32_16x16x32_f16(a, bf[g][cc], acc[g], 0, 0, 0);
            }

            const int nxt = cur ^ 1;
            {
                float ghr = acc[0][0] + bias_[0];
                float ghz = acc[1][0] + bias_[1];
                float ghn = acc[2][0] + bias_[2];
                float r = sigmoidf_(xv[0] + ghr);
                float z = sigmoidf_(xv[1] + ghz);
                float nn = tanh_fast(xv[2] + r * ghn);
                float hv = (1.f - z) * nn + z * hold;
                hold = hv;
                if (hi == 0) {
                    _Float16 h16 = (_Float16)hv;
                    hbuf[nxt][unit] = h16;
                    if (isL0) hbase[(size_t)t * H_ + unit] = h16;   // coalesced f16 stream
                    else      ybase[(size_t)t * H_ + unit] = hv;
                }
            }
            // raw barrier: drain LDS only; keep xp prefetch + stores in flight
            asm volatile("s_waitcnt lgkmcnt(0)" ::: "memory");
            __builtin_amdgcn_s_barrier();
            asm volatile("" ::: "memory");
            cur = nxt;
        }
        if (isL0) {
            asm volatile("s_waitcnt vmcnt(0)" ::: "memory");
            __syncthreads();
            if (tid == 0) {
                __threadfence();
                __hip_atomic_store(&flags[b * NCH + c], 1, __ATOMIC_RELEASE,
                                   __HIP_MEMORY_SCOPE_AGENT);
            }
        }
    }
}

// ---------------- prep: gat_W transpose + w_ih1 -> f16 ----------------
__global__ void gatw_t(const float* __restrict__ gw, float* __restrict__ W2)
{
    int idx = blockIdx.x * 256 + threadIdx.x;
    int n = idx >> 8, d = idx & 255;
    W2[idx] = gw[(size_t)(n >> 6) * 16384 + (size_t)d * 64 + (n & 63)];
}

__global__ void prep_wih1(const float* __restrict__ w, _Float16* __restrict__ wh)
{
    int i = (blockIdx.x * 256 + threadIdx.x) * 4; // 196608 elems
    float4 v = *(const float4*)(w + i);
    wh[i + 0] = (_Float16)v.x; wh[i + 1] = (_Float16)v.y;
    wh[i + 2] = (_Float16)v.z; wh[i + 3] = (_Float16)v.w;
}

// ---------------- e1/e2 ----------------
__global__ __launch_bounds__(256) void gat_e(
    const float* __restrict__ hk, const float* __restrict__ ga,
    float* __restrict__ e1, float* __restrict__ e2)
{
    __shared__ float tile[128][65];
    __shared__ float a1s[64], a2s[64];
    const int tt = blockIdx.x, k = blockIdx.y, b = blockIdx.z;
    const int tid = threadIdx.x;
    if (tid < 64) { a1s[tid] = ga[k * 128 + tid]; a2s[tid] = ga[k * 128 + 64 + tid]; }
    #pragma unroll
    for (int rep = 0; rep < 32; ++rep) {
        int idx = rep * 256 + tid; int tl = idx >> 6, f = idx & 63;
        tile[tl][f] = hk[((size_t)(b * 1024 + tt * 128 + tl)) * 256 + k * 64 + f];
    }
    __syncthreads();
    if (tid < 128) {
        float s1 = 0.f, s2 = 0.f;
        #pragma unroll 8
        for (int f = 0; f < 64; ++f) {
            float hv = tile[tid][f];
            s1 += hv * a1s[f]; s2 += hv * a2s[f];
        }
        const size_t o = (size_t)(b * 4 + k) * 1024 + tt * 128 + tid;
        e1[o] = s1; e2[o] = s2;
    }
}

// ---------------- GAT attention (MFMA PV, monotone-leaky exact max) ----------------
__global__ __launch_bounds__(256) void gat_attn(
    const float* __restrict__ hk, const float* __restrict__ e1,
    const float* __restrict__ e2, float* __restrict__ outp)
{
    __shared__ _Float16 hkT[64][72];
    __shared__ float e1s[64], e2s[64], lssh[64];
    __shared__ float red[4];
    const int tid = threadIdx.x;
    const int wv = tid >> 6, lane = tid & 63;
    const int col = lane & 15, hi = lane >> 4;
    const int tt = blockIdx.x, k = blockIdx.y, b = blockIdx.z;
    const int t0 = tt * 64;
    const float* e2row = e2 + (size_t)(b * 4 + k) * 1024;
    if (tid < 64) e1s[tid] = e1[(size_t)(b * 4 + k) * 1024 + t0 + tid];
    float m = -3.4e38f;
    for (int i = tid; i < 1024; i += 256) m = fmaxf(m, e2row[i]);
    #pragma unroll
    for (int off = 1; off < 64; off <<= 1) m = fmaxf(m, __shfl_xor(m, off));
    if (lane == 0) red[wv] = m;
    __syncthreads();
    const float e2max = fmaxf(fmaxf(red[0], red[1]), fmaxf(red[2], red[3]));
    const float e1A = e1s[wv * 16 + col];
    const float eAm = e1A + e2max;
    const float mA = (eAm > 0.f) ? eAm : 0.2f * eAm;

    float lsum = 0.f;
    f32x4 oacc[4] = {};
    const int vs = tid & 63, vfblk = (tid >> 6) * 16;
    for (int st = 0; st < 16; ++st) {
        {
            const float* hp = hk + ((size_t)(b * 1024 + st * 64 + vs)) * 256 + k * 64 + vfblk;
            float4 v0 = *(const float4*)hp, v1 = *(const float4*)(hp + 4);
            float4 v2 = *(const float4*)(hp + 8), v3 = *(const float4*)(hp + 12);
            float vv[16] = {v0.x, v0.y, v0.z, v0.w, v1.x, v1.y, v1.z, v1.w,
                            v2.x, v2.y, v2.z, v2.w, v3.x, v3.y, v3.z, v3.w};
            #pragma unroll
            for (int i = 0; i < 16; ++i) hkT[vfblk + i][vs] = (_Float16)vv[i];
        }
        if (tid < 64) e2s[tid] = e2row[st * 64 + tid];
        __syncthreads();
        #pragma unroll
        for (int c = 0; c < 2; ++c) {
            f16x8 af;
            #pragma unroll
            for (int i = 0; i < 8; ++i) {
                float e = e1A + e2s[c * 32 + hi * 8 + i];
                e = (e > 0.f) ? e : 0.2f * e;
                float pv = __expf(e - mA);
                _Float16 p16 = (_Float16)pv;
                af[i] = p16;
                lsum += (float)p16;
            }
            #pragma unroll
            for (int j = 0; j < 4; ++j) {
                f16x8 bfr = *(const f16x8*)&hkT[j * 16 + col][c * 32 + hi * 8];
                oacc[j] = __builtin_amdgcn_mfma_f32_16x16x32_f16(af, bfr, oacc[j], 0, 0, 0);
            }
        }
        __syncthreads();
    }
    lsum += __shfl_xor(lsum, 16);
    lsum += __shfl_xor(lsum, 32);
    if (hi == 0) lssh[wv * 16 + col] = lsum;
    #pragma unroll
    for (int r = 0; r < 4; ++r) {
        const float inv = 1.f / lssh[wv * 16 + hi * 4 + r];
        #pragma unroll
        for (int j = 0; j < 4; ++j)
            outp[((size_t)(b * 1024 + t0 + wv * 16 + hi * 4 + r)) * 256 + k * 64 + j * 16 + col]
                = oacc[j][r] * inv;
    }
}

// ---------------- residual + LayerNorm ----------------
__global__ __launch_bounds__(64) void add_ln(
    const float* __restrict__ a, const float* bb,
    const float* __restrict__ gamma, const float* __restrict__ beta,
    float* outp)
{
    const int row = blockIdx.x;
    const int lane = threadIdx.x;
    const size_t base = (size_t)row * 256 + lane * 4;
    float4 va = *(const float4*)(a + base);
    float4 vb = *(const float4*)(bb + base);
    float xv[4] = {va.x + vb.x, va.y + vb.y, va.z + vb.z, va.w + vb.w};
    float s = xv[0] + xv[1] + xv[2] + xv[3];
    float s2 = xv[0] * xv[0] + xv[1] * xv[1] + xv[2] * xv[2] + xv[3] * xv[3];
    #pragma unroll
    for (int off = 32; off >= 1; off >>= 1) {
        s += __shfl_xor(s, off);
        s2 += __shfl_xor(s2, off);
    }
    const float mu = s * (1.f / 256.f);
    const float var = s2 * (1.f / 256.f) - mu * mu;
    const float rs = rsqrtf(var + 1e-5f);
    float4 g4 = *(const float4*)(gamma + lane * 4);
    float4 b4 = *(const float4*)(beta + lane * 4);
    float4 ov;
    ov.x = (xv[0] - mu) * rs * g4.x + b4.x;
    ov.y = (xv[1] - mu) * rs * g4.y + b4.y;
    ov.z = (xv[2] - mu) * rs * g4.z + b4.z;
    ov.w = (xv[3] - mu) * rs * g4.w + b4.w;
    *(float4*)(outp + base) = ov;
}

// ---------------- MHA flash attention (MFMA QK^T + PV) ----------------
__global__ __launch_bounds__(256) void mha_attn(const float* __restrict__ qkv, float* __restrict__ o)
{
    __shared__ _Float16 ks[64][72];
    __shared__ _Float16 vts[64][72];
    __shared__ _Float16 ps[64][72];
    const int tid = threadIdx.x;
    const int wv = tid >> 6, lane = tid & 63;
    const int col = lane & 15, hi = lane >> 4;
    const int tt = blockIdx.x, h = blockIdx.y, b = blockIdx.z;
    const int t0 = tt * 64;
    const float* base = qkv + (size_t)b * 1024 * 768;

    f16x8 qf[2];
    #pragma unroll
    for (int c = 0; c < 2; ++c) {
        const float* src = base + (size_t)(t0 + wv * 16 + col) * 768 + h * 64 + c * 32 + hi * 8;
        float4 u0 = *(const float4*)src, u1 = *(const float4*)(src + 4);
        u0.x *= 0.125f; u0.y *= 0.125f; u0.z *= 0.125f; u0.w *= 0.125f;
        u1.x *= 0.125f; u1.y *= 0.125f; u1.z *= 0.125f; u1.w *= 0.125f;
        qf[c] = pack8(u0, u1);
    }
    f32x4 oacc[4] = {};
    float mrow[4] = {-3.4e38f, -3.4e38f, -3.4e38f, -3.4e38f};
    float lrow[4] = {};
    const int srow = tid >> 2, sdblk = (tid & 3) * 16;
    const int vs = tid & 63, vdblk = (tid >> 6) * 16;

    for (int st = 0; st < 16; ++st) {
        {
            const float* kp = base + (size_t)(st * 64 + srow) * 768 + 256 + h * 64 + sdblk;
            float4 k0 = *(const float4*)kp, k1 = *(const float4*)(kp + 4);
            float4 k2 = *(const float4*)(kp + 8), k3 = *(const float4*)(kp + 12);
            *(f16x8*)&ks[srow][sdblk] = pack8(k0, k1);
            *(f16x8*)&ks[srow][sdblk + 8] = pack8(k2, k3);
            const float* vp = base + (size_t)(st * 64 + vs) * 768 + 512 + h * 64 + vdblk;
            float4 v0 = *(const float4*)vp, v1 = *(const float4*)(vp + 4);
            float4 v2 = *(const float4*)(vp + 8), v3 = *(const float4*)(vp + 12);
            float vv[16] = {v0.x, v0.y, v0.z, v0.w, v1.x, v1.y, v1.z, v1.w,
                            v2.x, v2.y, v2.z, v2.w, v3.x, v3.y, v3.z, v3.w};
            #pragma unroll
            for (int i = 0; i < 16; ++i) vts[vdblk + i][vs] = (_Float16)vv[i];
        }
        __syncthreads();
        f32x4 sacc[4] = {};
        #pragma unroll
        for (int c = 0; c < 2; ++c) {
            #pragma unroll
            for (int j = 0; j < 4; ++j) {
                f16x8 bfr = *(const f16x8*)&ks[j * 16 + col][c * 32 + hi * 8];
                sacc[j] = __builtin_amdgcn_mfma_f32_16x16x32_f16(qf[c], bfr, sacc[j], 0, 0, 0);
            }
        }
        #pragma unroll
        for (int r = 0; r < 4; ++r) {
            float tm = fmaxf(fmaxf(sacc[0][r], sacc[1][r]), fmaxf(sacc[2][r], sacc[3][r]));
            tm = fmaxf(tm, __shfl_xor(tm, 1));
            tm = fmaxf(tm, __shfl_xor(tm, 2));
            tm = fmaxf(tm, __shfl_xor(tm, 4));
            tm = fmaxf(tm, __shfl_xor(tm, 8));
            const float mn = fmaxf(mrow[r], tm);
            const float corr = __expf(mrow[r] - mn);
            mrow[r] = mn;
            float lsum = 0.f;
            #pragma unroll
            for (int j = 0; j < 4; ++j) {
                float pv = __expf(sacc[j][r] - mn);
                _Float16 p16 = (_Float16)pv;
                ps[wv * 16 + hi * 4 + r][j * 16 + col] = p16;
                lsum += (float)p16;
            }
            lsum += __shfl_xor(lsum, 1);
            lsum += __shfl_xor(lsum, 2);
            lsum += __shfl_xor(lsum, 4);
            lsum += __shfl_xor(lsum, 8);
            lrow[r] = lrow[r] * corr + lsum;
            #pragma unroll
            for (int j = 0; j < 4; ++j) oacc[j][r] *= corr;
        }
        #pragma unroll
        for (int c = 0; c < 2; ++c) {
            f16x8 a = *(const f16x8*)&ps[wv * 16 + col][c * 32 + hi * 8];
            #pragma unroll
            for (int j = 0; j < 4; ++j) {
                f16x8 bfr = *(const f16x8*)&vts[j * 16 + col][c * 32 + hi * 8];
                oacc[j] = __builtin_amdgcn_mfma_f32_16x16x32_f16(a, bfr, oacc[j], 0, 0, 0);
            }
        }
        __syncthreads();
    }
    float inv[4];
    #pragma unroll
    for (int r = 0; r < 4; ++r) inv[r] = 1.f / lrow[r];
    #pragma unroll
    for (int j = 0; j < 4; ++j)
        #pragma unroll
        for (int r = 0; r < 4; ++r)
            o[((size_t)(b * 1024 + t0 + wv * 16 + hi * 4 + r)) * 256 + h * 64 + j * 16 + col]
                = oacc[j][r] * inv[r];
}

// ---------------- mean over T ----------------
__global__ __launch_bounds__(256) void pool_mean(const float* __restrict__ o, float* __restrict__ opool)
{
    const int b = blockIdx.x >> 3, chunk = blockIdx.x & 7;
    const int d = threadIdx.x;
    float s = 0.f;
    for (int t = chunk * 128; t < chunk * 128 + 128; ++t)
        s += o[((size_t)(b * 1024 + t)) * 256 + d];
    atomicAdd(&opool[b * 256 + d], s * (1.f / 1024.f));
}

// ---------------- head ----------------
__global__ __launch_bounds__(256) void head_k(
    const float* __restrict__ opool, const float* __restrict__ wout, const float* __restrict__ bout,
    const float* __restrict__ f1w, const float* __restrict__ f1b,
    const float* __restrict__ f2w, const float* __restrict__ f2b,
    float* __restrict__ outp)
{
    __shared__ float op[256], pooled[256], hid[128];
    const int b = blockIdx.x, e = threadIdx.x;
    op[e] = opool[b * 256 + e];
    __syncthreads();
    float s = bout[e];
    for (int d = 0; d < 256; d += 4) {
        float4 w4 = *(const float4*)(wout + (size_t)e * 256 + d);
        s += op[d] * w4.x + op[d + 1] * w4.y + op[d + 2] * w4.z + op[d + 3] * w4.w;
    }
    pooled[e] = s;
    __syncthreads();
    if (e < 128) {
        float s2 = f1b[e];
        for (int d = 0; d < 256; d += 4) {
            float4 w4 = *(const float4*)(f1w + (size_t)e * 256 + d);
            s2 += pooled[d] * w4.x + pooled[d + 1] * w4.y + pooled[d + 2] * w4.z + pooled[d + 3] * w4.w;
        }
        hid[e] = fmaxf(s2, 0.f);
    }
    __syncthreads();
    if (e < 2) {
        float s3 = f2b[e];
        for (int j = 0; j < 128; ++j) s3 += hid[j] * f2w[e * 128 + j];
        outp[b * 2 + e] = s3;
    }
}

extern "C" void kernel_launch(void* const* d_in, const int* in_sizes, int n_in,
                              void* d_out, int out_size, void* d_ws, size_t ws_size,
                              hipStream_t stream)
{
    const float* x         = (const float*)d_in[0];
    const float* w_ih0     = (const float*)d_in[1];
    const float* w_hh0     = (const float*)d_in[2];
    const float* b_ih0     = (const float*)d_in[3];
    const float* b_hh0     = (const float*)d_in[4];
    const float* w_ih1     = (const float*)d_in[5];
    const float* w_hh1     = (const float*)d_in[6];
    const float* b_ih1     = (const float*)d_in[7];
    const float* b_hh1     = (const float*)d_in[8];
    const float* gat_W     = (const float*)d_in[9];
    const float* gat_a     = (const float*)d_in[10];
    const float* ln_g      = (const float*)d_in[11];
    const float* ln_b      = (const float*)d_in[12];
    const float* mha_in_w  = (const float*)d_in[13];
    const float* mha_in_b  = (const float*)d_in[14];
    const float* mha_out_w = (const float*)d_in[15];
    const float* mha_out_b = (const float*)d_in[16];
    const float* fc1_w     = (const float*)d_in[17];
    const float* fc1_b     = (const float*)d_in[18];
    const float* fc2_w     = (const float*)d_in[19];
    const float* fc2_b     = (const float*)d_in[20];
    float* out = (float*)d_out;

    float* xpbuf = (float*)d_ws;                       // [B*T][768] xp0 -> xp1 (in place)
    float* buf1  = xpbuf + (size_t)B_ * T_ * G3_;      // [B*T][256] (h1-f16 during scans; gat/h after)
    float* buf2  = buf1 + (size_t)B_ * T_ * H_;        // [B*T][256] (gru_out)
    float* buf3  = buf2 + (size_t)B_ * T_ * H_;        // [B*T][256] (hk / o)
    float* W2    = buf3 + (size_t)B_ * T_ * H_;        // 65536
    float* e1    = W2 + 65536;
    float* e2    = e1 + 65536;
    float* opool = e2 + 65536;                         // 4096 floats
    int*   flags = (int*)(opool + 4096);               // 1024 ints (flagA[512] + flagB[512])
    _Float16* wih1h = (_Float16*)(flags + 1024);       // 196608 f16
    _Float16* h1buf = (_Float16*)buf1;                 // overlay: h1 (f16) during scans

    dim3 blk(256);
    prep_wih1<<<dim3(192), blk, 0, stream>>>(w_ih1, wih1h);
    // xp0 = x @ w_ih0^T + b_ih0   (M=B*T, N=G3, K=IN)
    gemm16<<<dim3(G3_ / 64, (B_ * T_) / 64), blk, 0, stream>>>(x, w_ih0, b_ih0, xpbuf, B_ * T_, G3_, IN_);
    // zero opool + flags (single contiguous region)
    hipMemsetAsync(opool, 0, 4096 * sizeof(float) + 1024 * sizeof(int), stream);
    // 3-stage pipelined scans: L0 (0-15) -> G (16-31) -> L1 (32-47), 1024 threads
    fused_gru<<<dim3(48), dim3(1024), 0, stream>>>(xpbuf, w_hh0, b_hh0, w_hh1, b_hh1,
                                                   wih1h, b_ih1, h1buf, buf2, flags);
    // gat_W transpose (W2 only feeds the hk GEMM below -> off the scan's critical path)
    gatw_t<<<dim3(256), blk, 0, stream>>>(gat_W, W2);
    // hk = gru_out @ W2^T -> buf3   (M=B*T, N=H, K=H)
    gemm16<<<dim3(H_ / 64, (B_ * T_) / 64), blk, 0, stream>>>(buf2, W2, nullptr, buf3, B_ * T_, H_, H_);
    gat_e<<<dim3(8, 4, 16), blk, 0, stream>>>(buf3, gat_a, e1, e2);
    gat_attn<<<dim3(16, 4, 16), blk, 0, stream>>>(buf3, e1, e2, buf1);
    add_ln<<<dim3(B_ * T_), dim3(64), 0, stream>>>(buf2, buf1, ln_g, ln_b, buf1);
    // qkv = h @ mha_in_w^T + b -> xpbuf   (M=B*T, N=G3, K=H)
    gemm16<<<dim3(G3_ / 64, (B_ * T_) / 64), blk, 0, stream>>>(buf1, mha_in_w, mha_in_b, xpbuf, B_ * T_, G3_, H_);
    mha_attn<<<dim3(16, 4, 16), blk, 0, stream>>>(xpbuf, buf3);
    pool_mean<<<dim3(128), blk, 0, stream>>>(buf3, opool);
    head_k<<<dim3(16), blk, 0, stream>>>(opool, mha_out_w, mha_out_b, fc1_w, fc1_b, fc2_w, fc2_b, out);
}